// Round 1
// baseline (1141.443 us; speedup 1.0000x reference)
//
#include <hip/hip_runtime.h>
#include <hip/hip_bf16.h>

#define TOKENS 4096
#define DMODEL 768
#define DHID   3072
#define NEXP   8

#define BM  32
#define CH  128              // hidden-chunk size
#define KB  128              // k-block for stage-1 staging
#define NCH (DHID / CH)      // 24
#define NKB (DMODEL / KB)    // 6
#define NOB (DMODEL / 128)   // 6 output 128-col blocks

typedef __bf16 bf16x8 __attribute__((ext_vector_type(8)));
typedef float  f32x4  __attribute__((ext_vector_type(4)));
typedef unsigned short ushort_t;

__device__ __forceinline__ float gelu_tanh(float x) {
    // jax.nn.gelu default (approximate=True): 0.5x(1+tanh(sqrt(2/pi)(x+0.044715x^3)))
    float z = 0.7978845608028654f * (x + 0.044715f * x * x * x);
    float t = 1.0f - 2.0f / (__expf(2.0f * z) + 1.0f);
    return 0.5f * x * (1.0f + t);
}

// ---------------- x -> bf16 ----------------
__global__ void k_cvt_x(const float* __restrict__ x, ushort_t* __restrict__ xb) {
    int i = (blockIdx.x * 256 + threadIdx.x) * 4;
    float4 v = *(const float4*)(x + i);
    ushort4 o;
    o.x = __builtin_bit_cast(ushort_t, (__bf16)v.x);
    o.y = __builtin_bit_cast(ushort_t, (__bf16)v.y);
    o.z = __builtin_bit_cast(ushort_t, (__bf16)v.z);
    o.w = __builtin_bit_cast(ushort_t, (__bf16)v.w);
    *(ushort4*)(xb + i) = o;
}

// ---------------- batched transpose + convert: in fp32 [R][C] -> out bf16 [C][R] ----------------
__global__ void k_transpose_cvt(const float* __restrict__ in, ushort_t* __restrict__ out,
                                int R, int C) {
    __shared__ float tile[32][33];
    int bx = blockIdx.x, by = blockIdx.y, bz = blockIdx.z;
    int tx = threadIdx.x & 31, ty = threadIdx.x >> 5;   // 32 x 8
    const float* ip = in + (size_t)bz * R * C;
    ushort_t* op = out + (size_t)bz * R * C;
#pragma unroll
    for (int i = 0; i < 4; ++i) {
        int r = by * 32 + ty + i * 8;
        int c = bx * 32 + tx;
        tile[ty + i * 8][tx] = ip[(size_t)r * C + c];
    }
    __syncthreads();
#pragma unroll
    for (int i = 0; i < 4; ++i) {
        int c = bx * 32 + ty + i * 8;   // output row (C index)
        int r = by * 32 + tx;           // output col (R index)
        float f = tile[tx][ty + i * 8];
        op[(size_t)c * R + r] = __builtin_bit_cast(ushort_t, (__bf16)f);
    }
}

// ---------------- router: fp32, wave per token ----------------
__global__ void k_router(const float* __restrict__ x, const float* __restrict__ Wr,
                         const float* __restrict__ br, int* __restrict__ cnt,
                         int* __restrict__ tok, float* __restrict__ wgt) {
    int wv = threadIdx.x >> 6;
    int lane = threadIdx.x & 63;
    int t = blockIdx.x * 4 + wv;
    const float* xr = x + (size_t)t * DMODEL;
    float4 xv[3];
#pragma unroll
    for (int j = 0; j < 3; ++j) xv[j] = *(const float4*)(xr + (j * 64 + lane) * 4);
    float lg[8];
#pragma unroll
    for (int e = 0; e < 8; ++e) {
        float s = 0.f;
#pragma unroll
        for (int j = 0; j < 3; ++j) {
            int base = (j * 64 + lane) * 4;
            s += xv[j].x * Wr[(base + 0) * 8 + e];
            s += xv[j].y * Wr[(base + 1) * 8 + e];
            s += xv[j].z * Wr[(base + 2) * 8 + e];
            s += xv[j].w * Wr[(base + 3) * 8 + e];
        }
#pragma unroll
        for (int o = 32; o > 0; o >>= 1) s += __shfl_xor(s, o);
        lg[e] = s + br[e];
    }
    if (lane == 0) {
        int e0 = 0; float b0 = lg[0];
#pragma unroll
        for (int e = 1; e < 8; ++e) if (lg[e] > b0) { b0 = lg[e]; e0 = e; }
        int e1 = -1; float b1v = -1e30f;
#pragma unroll
        for (int e = 0; e < 8; ++e) if (e != e0 && lg[e] > b1v) { b1v = lg[e]; e1 = e; }
        float w0 = 1.f / (1.f + __expf(b1v - b0));   // softmax over the top-2 logits
        float w1 = 1.f - w0;
        int p0 = atomicAdd(&cnt[e0], 1);
        tok[e0 * TOKENS + p0] = t; wgt[e0 * TOKENS + p0] = w0;
        int p1 = atomicAdd(&cnt[e1], 1);
        tok[e1 * TOKENS + p1] = t; wgt[e1 * TOKENS + p1] = w1;
    }
}

// ---------------- fused FFN per expert-tile ----------------
__launch_bounds__(512)
__global__ void k_ffn(const ushort_t* __restrict__ xb, const ushort_t* __restrict__ W1t,
                      const ushort_t* __restrict__ W2t, const float* __restrict__ b1,
                      const float* __restrict__ b2, const int* __restrict__ cnt,
                      const int* __restrict__ tok, const float* __restrict__ wgt,
                      float* __restrict__ out) {
    const int e = blockIdx.y;
    const int ce = cnt[e];
    const int m0 = blockIdx.x * BM;
    if (m0 >= ce) return;
    const int nrow = min(BM, ce - m0);

    __shared__ ushort_t Xs[BM * KB];     // [32][128] rows 256B, swizzled
    __shared__ ushort_t Ws[128 * KB];    // [128][128] rows 256B, swizzled (W1 chunk / W2 chunk)
    __shared__ ushort_t Hs[BM * CH];     // [32][128] rows 256B, swizzled
    __shared__ int   stok[BM];
    __shared__ float swt[BM];

    const int tid = threadIdx.x;
    if (tid < BM) {
        int idx = m0 + ((tid < nrow) ? tid : 0);
        stok[tid] = tok[e * TOKENS + idx];
        swt[tid]  = (tid < nrow) ? wgt[e * TOKENS + m0 + tid] : 0.f;
    }
    __syncthreads();

    const int lane = tid & 63;
    const int w    = tid >> 6;     // 0..7
    const int rowt = w >> 2;       // 0..1  (row tile of 16)
    const int cq   = w & 3;        // 0..3  (col quarter)
    const int jc   = lane & 15;
    const int kg   = lane >> 4;

    char* XsB = (char*)Xs;
    char* WsB = (char*)Ws;
    char* HsB = (char*)Hs;

    // A-fragment addressing (same pattern for Xs and Hs: rows 256B)
    const int arow  = rowt * 16 + jc;
    const int a_base = arow * 256 + kg * 16;        // + ks*64, then ^ a_swz
    const int a_swz  = (arow & 7) << 4;
    const int b_swz  = (jc & 7) << 4;

    f32x4 acc[NOB][2] = {};

    // staging maps
    const int xs_row = tid >> 4;
    const int xs_cc  = tid & 15;
    const int xs_addr = (xs_row * 256 + xs_cc * 16) ^ ((xs_row & 7) << 4);
    const int xs_tok = stok[xs_row];
    int ws_row[4], ws_addr[4];
#pragma unroll
    for (int it = 0; it < 4; ++it) {
        int c = it * 512 + tid;
        int r = c >> 4, cc = c & 15;
        ws_row[it] = r;
        ws_addr[it] = (r * 256 + cc * 16) ^ ((r & 7) << 4);
    }
    const int ws_cc8 = (tid & 15) * 8;

    for (int hc = 0; hc < NCH; ++hc) {
        f32x4 hacc[2] = {};
        // ---- stage 1: Hc = gelu(X @ W1[:, chunk] + b1) ----
        for (int kb = 0; kb < NKB; ++kb) {
            __syncthreads();   // previous users of Ws/Xs done
            {
                uint4 v = *(const uint4*)(xb + (size_t)xs_tok * DMODEL + kb * KB + xs_cc * 8);
                *(uint4*)(XsB + xs_addr) = v;
            }
#pragma unroll
            for (int it = 0; it < 4; ++it) {
                int h = hc * CH + ws_row[it];
                uint4 v = *(const uint4*)(W1t + ((size_t)e * DHID + h) * DMODEL + kb * KB + ws_cc8);
                *(uint4*)(WsB + ws_addr[it]) = v;
            }
            __syncthreads();
            bf16x8 af[4];
#pragma unroll
            for (int ks = 0; ks < 4; ++ks)
                af[ks] = *(const bf16x8*)(XsB + ((a_base + ks * 64) ^ a_swz));
#pragma unroll
            for (int t = 0; t < 2; ++t) {
                int colt = cq + t * 4;
                int bb = (colt * 16 + jc) * 256 + kg * 16;
#pragma unroll
                for (int ks = 0; ks < 4; ++ks) {
                    bf16x8 bf = *(const bf16x8*)(WsB + ((bb + ks * 64) ^ b_swz));
                    hacc[t] = __builtin_amdgcn_mfma_f32_16x16x32_bf16(af[ks], bf, hacc[t], 0, 0, 0);
                }
            }
        }
        // bias + gelu -> Hs (bf16)
#pragma unroll
        for (int t = 0; t < 2; ++t) {
            int colt = cq + t * 4;
            int col = colt * 16 + jc;
            float bb = b1[e * DHID + hc * CH + col];
#pragma unroll
            for (int r = 0; r < 4; ++r) {
                int row = rowt * 16 + kg * 4 + r;
                float hv = gelu_tanh(hacc[t][r] + bb);
                int addr = (row * 256 + col * 2) ^ ((row & 7) << 4);
                *(ushort_t*)(HsB + addr) = __builtin_bit_cast(ushort_t, (__bf16)hv);
            }
        }
        __syncthreads();   // Hs ready; all stage-1 reads of Ws complete

        // ---- stage 2: Y += Hc @ W2[chunk, :] ----
        bf16x8 af2[4];
#pragma unroll
        for (int ks = 0; ks < 4; ++ks)
            af2[ks] = *(const bf16x8*)(HsB + ((a_base + ks * 64) ^ a_swz));
#pragma unroll
        for (int ob = 0; ob < NOB; ++ob) {
#pragma unroll
            for (int it = 0; it < 4; ++it) {
                int o = ob * 128 + ws_row[it];
                uint4 v = *(const uint4*)(W2t + ((size_t)e * DMODEL + o) * DHID + hc * CH + ws_cc8);
                *(uint4*)(WsB + ws_addr[it]) = v;
            }
            __syncthreads();
#pragma unroll
            for (int t = 0; t < 2; ++t) {
                int colt = cq + t * 4;
                int bb = (colt * 16 + jc) * 256 + kg * 16;
#pragma unroll
                for (int ks = 0; ks < 4; ++ks) {
                    bf16x8 bf = *(const bf16x8*)(WsB + ((bb + ks * 64) ^ b_swz));
                    acc[ob][t] = __builtin_amdgcn_mfma_f32_16x16x32_bf16(af2[ks], bf, acc[ob][t], 0, 0, 0);
                }
            }
            __syncthreads();
        }
    }

    // ---- epilogue: weighted atomic combine ----
#pragma unroll
    for (int ob = 0; ob < NOB; ++ob) {
#pragma unroll
        for (int t = 0; t < 2; ++t) {
            int col = ob * 128 + (cq + t * 4) * 16 + jc;
            float b2v = b2[e * DMODEL + col];
#pragma unroll
            for (int r = 0; r < 4; ++r) {
                int row = rowt * 16 + kg * 4 + r;
                if (row < nrow) {
                    float v = (acc[ob][t][r] + b2v) * swt[row];
                    atomicAdd(&out[(size_t)stok[row] * DMODEL + col], v);
                }
            }
        }
    }
}

// ---------------- in-place LayerNorm, wave per token ----------------
__global__ void k_ln(float* __restrict__ out, const float* __restrict__ g,
                     const float* __restrict__ b) {
    int wv = threadIdx.x >> 6, lane = threadIdx.x & 63;
    int t = blockIdx.x * 4 + wv;
    float* row = out + (size_t)t * DMODEL;
    float4 v[3];
    float s = 0.f, ss = 0.f;
#pragma unroll
    for (int j = 0; j < 3; ++j) {
        v[j] = *(const float4*)(row + (j * 64 + lane) * 4);
        s  += v[j].x + v[j].y + v[j].z + v[j].w;
        ss += v[j].x * v[j].x + v[j].y * v[j].y + v[j].z * v[j].z + v[j].w * v[j].w;
    }
#pragma unroll
    for (int o = 32; o > 0; o >>= 1) { s += __shfl_xor(s, o); ss += __shfl_xor(ss, o); }
    float mu = s * (1.f / 768.f);
    float var = ss * (1.f / 768.f) - mu * mu;
    float inv = rsqrtf(var + 1e-5f);
#pragma unroll
    for (int j = 0; j < 3; ++j) {
        int base = (j * 64 + lane) * 4;
        float4 gv = *(const float4*)(g + base);
        float4 bv = *(const float4*)(b + base);
        float4 o4;
        o4.x = (v[j].x - mu) * inv * gv.x + bv.x;
        o4.y = (v[j].y - mu) * inv * gv.y + bv.y;
        o4.z = (v[j].z - mu) * inv * gv.z + bv.z;
        o4.w = (v[j].w - mu) * inv * gv.w + bv.w;
        *(float4*)(row + base) = o4;
    }
}

extern "C" void kernel_launch(void* const* d_in, const int* in_sizes, int n_in,
                              void* d_out, int out_size, void* d_ws, size_t ws_size,
                              hipStream_t stream) {
    const float* x    = (const float*)d_in[0];
    const float* Wr   = (const float*)d_in[1];
    const float* br   = (const float*)d_in[2];
    const float* W1   = (const float*)d_in[3];
    const float* b1   = (const float*)d_in[4];
    const float* W2   = (const float*)d_in[5];
    const float* b2   = (const float*)d_in[6];
    const float* ln_g = (const float*)d_in[7];
    const float* ln_b = (const float*)d_in[8];
    float* out = (float*)d_out;

    char* ws = (char*)d_ws;
    int*      cnt = (int*)ws;                                 // 8 ints
    int*      tok = (int*)(ws + 1024);                        // 8*4096 ints
    float*    wgt = (float*)(ws + 1024 + 131072);             // 8*4096 floats
    ushort_t* xb  = (ushort_t*)(ws + 524288);                 // 4096*768 bf16
    ushort_t* W1t = (ushort_t*)(ws + 524288 + 6291456);       // 8*3072*768 bf16
    ushort_t* W2t = (ushort_t*)(ws + 524288 + 6291456 + 37748736);

    hipMemsetAsync(cnt, 0, 32, stream);
    hipMemsetAsync(d_out, 0, (size_t)out_size * sizeof(float), stream);

    k_cvt_x<<<dim3(TOKENS * DMODEL / (256 * 4)), dim3(256), 0, stream>>>(x, xb);
    k_transpose_cvt<<<dim3(DHID / 32, DMODEL / 32, NEXP), dim3(256), 0, stream>>>(W1, W1t, DMODEL, DHID);
    k_transpose_cvt<<<dim3(DMODEL / 32, DHID / 32, NEXP), dim3(256), 0, stream>>>(W2, W2t, DHID, DMODEL);
    k_router<<<dim3(TOKENS / 4), dim3(256), 0, stream>>>(x, Wr, br, cnt, tok, wgt);
    k_ffn<<<dim3(TOKENS / BM, NEXP), dim3(512), 0, stream>>>(xb, W1t, W2t, b1, b2, cnt, tok, wgt, out);
    k_ln<<<dim3(TOKENS / 4), dim3(256), 0, stream>>>(out, ln_g, ln_b);
}

// Round 2
// 492.948 us; speedup vs baseline: 2.3155x; 2.3155x over previous
//
#include <hip/hip_runtime.h>
#include <hip/hip_bf16.h>

#define TOKENS 4096
#define DMODEL 768
#define DHID   3072
#define NEXP   8

typedef __bf16 bf16x8 __attribute__((ext_vector_type(8)));
typedef float  f32x4  __attribute__((ext_vector_type(4)));
typedef unsigned short ushort_t;

__device__ __forceinline__ float gelu_tanh(float x) {
    // jax.nn.gelu default (approximate=True)
    float z = 0.7978845608028654f * (x + 0.044715f * x * x * x);
    float t = 1.0f - 2.0f / (__expf(2.0f * z) + 1.0f);
    return 0.5f * x * (1.0f + t);
}

__device__ __forceinline__ void gload16(const void* g, void* l) {
    __builtin_amdgcn_global_load_lds((const __attribute__((address_space(1))) void*)g,
                                     (__attribute__((address_space(3))) void*)l, 16, 0, 0);
}

// ---------------- x -> bf16 ----------------
__global__ void k_cvt_x(const float* __restrict__ x, ushort_t* __restrict__ xb) {
    int i = (blockIdx.x * 256 + threadIdx.x) * 4;
    float4 v = *(const float4*)(x + i);
    ushort4 o;
    o.x = __builtin_bit_cast(ushort_t, (__bf16)v.x);
    o.y = __builtin_bit_cast(ushort_t, (__bf16)v.y);
    o.z = __builtin_bit_cast(ushort_t, (__bf16)v.z);
    o.w = __builtin_bit_cast(ushort_t, (__bf16)v.w);
    *(ushort4*)(xb + i) = o;
}

// ---------------- batched transpose + convert: in fp32 [R][C] -> out bf16 [C][R] ----------------
__global__ void k_transpose_cvt(const float* __restrict__ in, ushort_t* __restrict__ out,
                                int R, int C) {
    __shared__ float tile[32][33];
    int bx = blockIdx.x, by = blockIdx.y, bz = blockIdx.z;
    int tx = threadIdx.x & 31, ty = threadIdx.x >> 5;   // 32 x 8
    const float* ip = in + (size_t)bz * R * C;
    ushort_t* op = out + (size_t)bz * R * C;
#pragma unroll
    for (int i = 0; i < 4; ++i) {
        int r = by * 32 + ty + i * 8;
        int c = bx * 32 + tx;
        tile[ty + i * 8][tx] = ip[(size_t)r * C + c];
    }
    __syncthreads();
#pragma unroll
    for (int i = 0; i < 4; ++i) {
        int c = bx * 32 + ty + i * 8;   // output row (C index)
        int r = by * 32 + tx;           // output col (R index)
        float f = tile[tx][ty + i * 8];
        op[(size_t)c * R + r] = __builtin_bit_cast(ushort_t, (__bf16)f);
    }
}

// ---------------- router: fp32, wave per token ----------------
__global__ void k_router(const float* __restrict__ x, const float* __restrict__ Wr,
                         const float* __restrict__ br, int* __restrict__ cnt,
                         int* __restrict__ tok, int* __restrict__ slot,
                         float* __restrict__ wslot) {
    int wv = threadIdx.x >> 6;
    int lane = threadIdx.x & 63;
    int t = blockIdx.x * 4 + wv;
    const float* xr = x + (size_t)t * DMODEL;
    float4 xv[3];
#pragma unroll
    for (int j = 0; j < 3; ++j) xv[j] = *(const float4*)(xr + (j * 64 + lane) * 4);
    float lg[8];
#pragma unroll
    for (int e = 0; e < 8; ++e) {
        float s = 0.f;
#pragma unroll
        for (int j = 0; j < 3; ++j) {
            int base = (j * 64 + lane) * 4;
            s += xv[j].x * Wr[(base + 0) * 8 + e];
            s += xv[j].y * Wr[(base + 1) * 8 + e];
            s += xv[j].z * Wr[(base + 2) * 8 + e];
            s += xv[j].w * Wr[(base + 3) * 8 + e];
        }
#pragma unroll
        for (int o = 32; o > 0; o >>= 1) s += __shfl_xor(s, o);
        lg[e] = s + br[e];
    }
    if (lane == 0) {
        int e0 = 0; float b0 = lg[0];
#pragma unroll
        for (int e = 1; e < 8; ++e) if (lg[e] > b0) { b0 = lg[e]; e0 = e; }
        int e1 = -1; float b1v = -1e30f;
#pragma unroll
        for (int e = 0; e < 8; ++e) if (e != e0 && lg[e] > b1v) { b1v = lg[e]; e1 = e; }
        float w0 = 1.f / (1.f + __expf(b1v - b0));   // renormalized top-2 softmax
        float w1 = 1.f - w0;
        int p0 = atomicAdd(&cnt[e0], 1);
        tok[e0 * TOKENS + p0] = t; slot[e0 * TOKENS + p0] = 2 * t;
        int p1 = atomicAdd(&cnt[e1], 1);
        tok[e1 * TOKENS + p1] = t; slot[e1 * TOKENS + p1] = 2 * t + 1;
        wslot[2 * t] = w0; wslot[2 * t + 1] = w1;
    }
}

// ---------------- tiled GEMM (m97 structure), gathered A rows ----------------
// A: [rows gathered via rdIdx] x K (bf16, row stride K)
// B: Wb[e][NC][K] (bf16, k-contiguous)
// out: row = wrIdx[gi], NC columns. GELU -> bf16 out, else fp32 out.
template<int BM, int K, int NC, bool GELU>
__launch_bounds__(256)
__global__ void k_gemm(const ushort_t* __restrict__ Abase, const int* __restrict__ rdIdx,
                       const ushort_t* __restrict__ Wb, const float* __restrict__ bias,
                       void* __restrict__ outp, const int* __restrict__ wrIdx,
                       const int* __restrict__ cnt) {
    const int e  = blockIdx.z;
    const int ce = cnt[e];
    const int m0 = blockIdx.x * BM;
    if (m0 >= ce) return;
    const int n0 = blockIdx.y * 128;

    __shared__ ushort_t As[BM * 64];
    __shared__ ushort_t Bs[128 * 64];

    const int tid  = threadIdx.x;
    const int lane = tid & 63;
    const int w    = tid >> 6;            // 0..3

    constexpr int CPW = BM / 32;          // A 1KB-chunks per wave
    const ushort_t* aSrc[CPW];
#pragma unroll
    for (int it = 0; it < CPW; ++it) {
        int row = (w * CPW + it) * 8 + (lane >> 3);
        int gi  = min(m0 + row, ce - 1);
        aSrc[it] = Abase + (size_t)rdIdx[e * TOKENS + gi] * K + (lane & 7) * 8;
    }
    const ushort_t* bSrc[4];
#pragma unroll
    for (int it = 0; it < 4; ++it) {
        int row = (w * 4 + it) * 8 + (lane >> 3);
        bSrc[it] = Wb + ((size_t)e * NC + n0 + row) * K + (lane & 7) * 8;
    }

    const int wrow = (w >> 1) * (BM / 2);
    const int wcol = (w & 1) * 64;
    constexpr int MR = BM / 32;
    f32x4 acc[MR][4] = {};

    char* AsB = (char*)As;
    char* BsB = (char*)Bs;
    const int fr = lane & 15, fg = lane >> 4;

    for (int kb = 0; kb < K / 64; ++kb) {
        __syncthreads();
#pragma unroll
        for (int it = 0; it < CPW; ++it)
            gload16(aSrc[it] + kb * 64, AsB + (w * CPW + it) * 1024);
#pragma unroll
        for (int it = 0; it < 4; ++it)
            gload16(bSrc[it] + kb * 64, BsB + (w * 4 + it) * 1024);
        __syncthreads();

        bf16x8 af[MR][2], bf[4][2];
#pragma unroll
        for (int mi = 0; mi < MR; ++mi)
#pragma unroll
            for (int ks = 0; ks < 2; ++ks)
                af[mi][ks] = *(const bf16x8*)(AsB + (wrow + mi * 16 + fr) * 128 + ks * 64 + fg * 16);
#pragma unroll
        for (int ni = 0; ni < 4; ++ni)
#pragma unroll
            for (int ks = 0; ks < 2; ++ks)
                bf[ni][ks] = *(const bf16x8*)(BsB + (wcol + ni * 16 + fr) * 128 + ks * 64 + fg * 16);
#pragma unroll
        for (int mi = 0; mi < MR; ++mi)
#pragma unroll
            for (int ni = 0; ni < 4; ++ni)
#pragma unroll
                for (int ks = 0; ks < 2; ++ks)
                    acc[mi][ni] = __builtin_amdgcn_mfma_f32_16x16x32_bf16(af[mi][ks], bf[ni][ks], acc[mi][ni], 0, 0, 0);
    }

    // epilogue
    float bv[4];
#pragma unroll
    for (int ni = 0; ni < 4; ++ni)
        bv[ni] = bias[e * NC + n0 + wcol + ni * 16 + fr];
#pragma unroll
    for (int mi = 0; mi < MR; ++mi) {
#pragma unroll
        for (int r = 0; r < 4; ++r) {
            int gi = m0 + wrow + mi * 16 + fg * 4 + r;
            if (gi < ce) {
                int orow = wrIdx[e * TOKENS + gi];
#pragma unroll
                for (int ni = 0; ni < 4; ++ni) {
                    int col = n0 + wcol + ni * 16 + fr;
                    float v = acc[mi][ni][r] + bv[ni];
                    if constexpr (GELU) {
                        v = gelu_tanh(v);
                        ((ushort_t*)outp)[(size_t)orow * NC + col] =
                            __builtin_bit_cast(ushort_t, (__bf16)v);
                    } else {
                        ((float*)outp)[(size_t)orow * NC + col] = v;
                    }
                }
            }
        }
    }
}

// ---------------- weighted 2-slot combine + LayerNorm, wave per token ----------------
__global__ void k_ln(const float* __restrict__ Y, const float* __restrict__ wslot,
                     const float* __restrict__ g, const float* __restrict__ b,
                     float* __restrict__ out) {
    int wv = threadIdx.x >> 6, lane = threadIdx.x & 63;
    int t = blockIdx.x * 4 + wv;
    const float* y0 = Y + (size_t)(2 * t) * DMODEL;
    const float* y1 = y0 + DMODEL;
    float w0 = wslot[2 * t], w1 = wslot[2 * t + 1];
    float4 v[3];
    float s = 0.f, ss = 0.f;
#pragma unroll
    for (int j = 0; j < 3; ++j) {
        int base = (j * 64 + lane) * 4;
        float4 a0 = *(const float4*)(y0 + base);
        float4 a1 = *(const float4*)(y1 + base);
        float4 c;
        c.x = w0 * a0.x + w1 * a1.x;
        c.y = w0 * a0.y + w1 * a1.y;
        c.z = w0 * a0.z + w1 * a1.z;
        c.w = w0 * a0.w + w1 * a1.w;
        v[j] = c;
        s  += c.x + c.y + c.z + c.w;
        ss += c.x * c.x + c.y * c.y + c.z * c.z + c.w * c.w;
    }
#pragma unroll
    for (int o = 32; o > 0; o >>= 1) { s += __shfl_xor(s, o); ss += __shfl_xor(ss, o); }
    float mu = s * (1.f / 768.f);
    float var = ss * (1.f / 768.f) - mu * mu;
    float inv = rsqrtf(var + 1e-5f);
    float* row = out + (size_t)t * DMODEL;
#pragma unroll
    for (int j = 0; j < 3; ++j) {
        int base = (j * 64 + lane) * 4;
        float4 gv = *(const float4*)(g + base);
        float4 bv = *(const float4*)(b + base);
        float4 o4;
        o4.x = (v[j].x - mu) * inv * gv.x + bv.x;
        o4.y = (v[j].y - mu) * inv * gv.y + bv.y;
        o4.z = (v[j].z - mu) * inv * gv.z + bv.z;
        o4.w = (v[j].w - mu) * inv * gv.w + bv.w;
        *(float4*)(row + base) = o4;
    }
}

extern "C" void kernel_launch(void* const* d_in, const int* in_sizes, int n_in,
                              void* d_out, int out_size, void* d_ws, size_t ws_size,
                              hipStream_t stream) {
    const float* x    = (const float*)d_in[0];
    const float* Wr   = (const float*)d_in[1];
    const float* br   = (const float*)d_in[2];
    const float* W1   = (const float*)d_in[3];
    const float* b1   = (const float*)d_in[4];
    const float* W2   = (const float*)d_in[5];
    const float* b2   = (const float*)d_in[6];
    const float* ln_g = (const float*)d_in[7];
    const float* ln_b = (const float*)d_in[8];
    float* out = (float*)d_out;

    char* ws = (char*)d_ws;
    int*      cnt   = (int*)(ws + 0);                    //    32 B
    int*      tok   = (int*)(ws + 4096);                 //   128 KB
    int*      slot  = (int*)(ws + 135168);               //   128 KB
    float*    wslot = (float*)(ws + 266240);             //    32 KB
    ushort_t* xb    = (ushort_t*)(ws + 327680);          //  6.29 MB
    ushort_t* W1t   = (ushort_t*)(ws + 6619136);         // 37.75 MB  [e][h][d]
    ushort_t* W2t   = (ushort_t*)(ws + 44367872);        // 37.75 MB  [e][o][h]
    ushort_t* H     = (ushort_t*)(ws + 82116608);        // 50.33 MB  [8192][3072] bf16
    float*    Y     = (float*)(ws + 132448256);          // 25.17 MB  [8192][768] f32

    hipMemsetAsync(cnt, 0, 32, stream);

    k_cvt_x<<<dim3(TOKENS * DMODEL / (256 * 4)), dim3(256), 0, stream>>>(x, xb);
    k_transpose_cvt<<<dim3(DHID / 32, DMODEL / 32, NEXP), dim3(256), 0, stream>>>(W1, W1t, DMODEL, DHID);
    k_transpose_cvt<<<dim3(DMODEL / 32, DHID / 32, NEXP), dim3(256), 0, stream>>>(W2, W2t, DHID, DMODEL);
    k_router<<<dim3(TOKENS / 4), dim3(256), 0, stream>>>(x, Wr, br, cnt, tok, slot, wslot);

    // stage A: H[slot] = gelu(X[tok] @ W1t^T + b1)   [K=768, NC=3072]
    k_gemm<128, DMODEL, DHID, true><<<dim3(TOKENS / 128, DHID / 128, NEXP), dim3(256), 0, stream>>>(
        xb, tok, W1t, b1, H, slot, cnt);
    // stage B: Y[slot] = H[slot] @ W2t^T + b2        [K=3072, NC=768]
    k_gemm<64, DHID, DMODEL, false><<<dim3(TOKENS / 64, DMODEL / 128, NEXP), dim3(256), 0, stream>>>(
        H, slot, W2t, b2, Y, slot, cnt);

    k_ln<<<dim3(TOKENS / 4), dim3(256), 0, stream>>>(Y, wslot, ln_g, ln_b, out);
}

// Round 3
// 373.275 us; speedup vs baseline: 3.0579x; 1.3206x over previous
//
#include <hip/hip_runtime.h>
#include <hip/hip_bf16.h>

#define TOKENS 4096
#define DMODEL 768
#define DHID   3072
#define NEXP   8
#define MAXTA  72     // max stage-A tiles: 8192/128 + 7
#define MAXTB  136    // max stage-B tiles: 8192/64 + 7

typedef __bf16 bf16x8 __attribute__((ext_vector_type(8)));
typedef float  f32x4  __attribute__((ext_vector_type(4)));
typedef unsigned short ushort_t;

__device__ __forceinline__ float gelu_tanh(float x) {
    // jax.nn.gelu default (approximate=True)
    float z = 0.7978845608028654f * (x + 0.044715f * x * x * x);
    float t = 1.0f - 2.0f / (__expf(2.0f * z) + 1.0f);
    return 0.5f * x * (1.0f + t);
}

__device__ __forceinline__ void gload16(const void* g, void* l) {
    __builtin_amdgcn_global_load_lds((const __attribute__((address_space(1))) void*)g,
                                     (__attribute__((address_space(3))) void*)l, 16, 0, 0);
}

// ---------------- batched transpose + convert: in fp32 [R][C] -> out bf16 [C][R] ----------------
__global__ void k_transpose_cvt(const float* __restrict__ in, ushort_t* __restrict__ out,
                                int R, int C) {
    __shared__ float tile[32][33];
    int bx = blockIdx.x, by = blockIdx.y, bz = blockIdx.z;
    int tx = threadIdx.x & 31, ty = threadIdx.x >> 5;   // 32 x 8
    const float* ip = in + (size_t)bz * R * C;
    ushort_t* op = out + (size_t)bz * R * C;
#pragma unroll
    for (int i = 0; i < 4; ++i) {
        int r = by * 32 + ty + i * 8;
        int c = bx * 32 + tx;
        tile[ty + i * 8][tx] = ip[(size_t)r * C + c];
    }
    __syncthreads();
#pragma unroll
    for (int i = 0; i < 4; ++i) {
        int c = bx * 32 + ty + i * 8;   // output row (C index)
        int r = by * 32 + tx;           // output col (R index)
        float f = tile[tx][ty + i * 8];
        op[(size_t)c * R + r] = __builtin_bit_cast(ushort_t, (__bf16)f);
    }
}

// ---------------- router: fp32 logits + top-2, fused x->bf16 cast ----------------
__global__ void k_router(const float* __restrict__ x, const float* __restrict__ Wr,
                         const float* __restrict__ br, int* __restrict__ cnt,
                         int* __restrict__ tok, int* __restrict__ slot,
                         float* __restrict__ wslot, ushort_t* __restrict__ xb) {
    int wv = threadIdx.x >> 6;
    int lane = threadIdx.x & 63;
    int t = blockIdx.x * 4 + wv;
    const float* xr = x + (size_t)t * DMODEL;
    float4 xv[3];
#pragma unroll
    for (int j = 0; j < 3; ++j) xv[j] = *(const float4*)(xr + (j * 64 + lane) * 4);
    // fused bf16 cast of x
#pragma unroll
    for (int j = 0; j < 3; ++j) {
        int base = (j * 64 + lane) * 4;
        ushort4 o;
        o.x = __builtin_bit_cast(ushort_t, (__bf16)xv[j].x);
        o.y = __builtin_bit_cast(ushort_t, (__bf16)xv[j].y);
        o.z = __builtin_bit_cast(ushort_t, (__bf16)xv[j].z);
        o.w = __builtin_bit_cast(ushort_t, (__bf16)xv[j].w);
        *(ushort4*)(xb + (size_t)t * DMODEL + base) = o;
    }
    float lg[8];
#pragma unroll
    for (int e = 0; e < 8; ++e) {
        float s = 0.f;
#pragma unroll
        for (int j = 0; j < 3; ++j) {
            int base = (j * 64 + lane) * 4;
            s += xv[j].x * Wr[(base + 0) * 8 + e];
            s += xv[j].y * Wr[(base + 1) * 8 + e];
            s += xv[j].z * Wr[(base + 2) * 8 + e];
            s += xv[j].w * Wr[(base + 3) * 8 + e];
        }
#pragma unroll
        for (int o = 32; o > 0; o >>= 1) s += __shfl_xor(s, o);
        lg[e] = s + br[e];
    }
    if (lane == 0) {
        int e0 = 0; float b0 = lg[0];
#pragma unroll
        for (int e = 1; e < 8; ++e) if (lg[e] > b0) { b0 = lg[e]; e0 = e; }
        int e1 = -1; float b1v = -1e30f;
#pragma unroll
        for (int e = 0; e < 8; ++e) if (e != e0 && lg[e] > b1v) { b1v = lg[e]; e1 = e; }
        float w0 = 1.f / (1.f + __expf(b1v - b0));   // renormalized top-2 softmax
        float w1 = 1.f - w0;
        int p0 = atomicAdd(&cnt[e0], 1);
        tok[e0 * TOKENS + p0] = t; slot[e0 * TOKENS + p0] = 2 * t;
        int p1 = atomicAdd(&cnt[e1], 1);
        tok[e1 * TOKENS + p1] = t; slot[e1 * TOKENS + p1] = 2 * t + 1;
        wslot[2 * t] = w0; wslot[2 * t + 1] = w1;
    }
}

// ---------------- tile scheduler: compact (expert, m0) tables ----------------
// sch[0]=nA, sch[1]=nB, sch[2..9]=baseH (exclusive prefix of cnt),
// sch[16..]=stage-A tiles (e<<20|m0, BM=128), sch[96..]=stage-B tiles (BM=64)
__global__ void k_sched(const int* __restrict__ cnt, int* __restrict__ sch) {
    if (threadIdx.x == 0) {
        int base = 0, na = 0, nb = 0;
        for (int e = 0; e < NEXP; ++e) {
            sch[2 + e] = base;
            int ce = cnt[e];
            for (int m = 0; m < ce; m += 128) sch[16 + na++] = (e << 20) | m;
            for (int m = 0; m < ce; m += 64)  sch[96 + nb++] = (e << 20) | m;
            base += ce;
        }
        sch[0] = na;
        sch[1] = nb;
    }
}

// ---------------- 2-phase double-buffered GEMM ----------------
// STAGE1: A rows gathered via tok, out = gelu(acc+b1) -> H bf16 (packed rows baseH[e]+gi)
// else:   A rows = packed H,        out = acc+b2 -> Y f32 (scattered rows slot[])
template<int BM, int K, int NC, bool STAGE1>
__launch_bounds__(256)
__global__ void k_gemm(const ushort_t* __restrict__ Abase, const int* __restrict__ tok,
                       const int* __restrict__ slot, const ushort_t* __restrict__ Wb,
                       const float* __restrict__ bias, void* __restrict__ outp,
                       const int* __restrict__ cnt, const int* __restrict__ sch) {
    const int nT = sch[STAGE1 ? 0 : 1];
    if ((int)blockIdx.x >= nT) return;
    const int ent = sch[(STAGE1 ? 16 : 96) + blockIdx.x];
    const int e = ent >> 20, m0 = ent & 0xFFFFF;
    const int ce = cnt[e];
    const int bH = sch[2 + e];
    const int n0 = blockIdx.y * 128;

    __shared__ ushort_t As[2][BM * 64];
    __shared__ ushort_t Bs[2][128 * 64];

    const int tid = threadIdx.x, lane = tid & 63, w = tid >> 6;
    constexpr int CPW = BM / 32;          // A 1KB-chunks per wave

    const ushort_t* aSrc[CPW];
#pragma unroll
    for (int it = 0; it < CPW; ++it) {
        int row = (w * CPW + it) * 8 + (lane >> 3);
        int gi = min(m0 + row, ce - 1);
        size_t r = STAGE1 ? (size_t)tok[e * TOKENS + gi] : (size_t)(bH + gi);
        aSrc[it] = Abase + r * K + (lane & 7) * 8;
    }
    const ushort_t* bSrc[4];
#pragma unroll
    for (int it = 0; it < 4; ++it) {
        int row = (w * 4 + it) * 8 + (lane >> 3);
        bSrc[it] = Wb + ((size_t)e * NC + n0 + row) * K + (lane & 7) * 8;
    }

    const int wrow = (w >> 1) * (BM / 2);
    const int wcol = (w & 1) * 64;
    constexpr int MR = BM / 32;
    f32x4 acc[MR][4] = {};
    const int fr = lane & 15, fg = lane >> 4;

    auto stage = [&](int kb, int b) {
        char* AsB = (char*)As[b];
        char* BsB = (char*)Bs[b];
#pragma unroll
        for (int it = 0; it < CPW; ++it)
            gload16(aSrc[it] + kb * 64, AsB + (w * CPW + it) * 1024);
#pragma unroll
        for (int it = 0; it < 4; ++it)
            gload16(bSrc[it] + kb * 64, BsB + (w * 4 + it) * 1024);
    };
    auto compute = [&](int b) {
        const char* AsB = (const char*)As[b];
        const char* BsB = (const char*)Bs[b];
        bf16x8 af[MR][2], bfr[4][2];
#pragma unroll
        for (int mi = 0; mi < MR; ++mi)
#pragma unroll
            for (int ks = 0; ks < 2; ++ks)
                af[mi][ks] = *(const bf16x8*)(AsB + (wrow + mi * 16 + fr) * 128 + ks * 64 + fg * 16);
#pragma unroll
        for (int ni = 0; ni < 4; ++ni)
#pragma unroll
            for (int ks = 0; ks < 2; ++ks)
                bfr[ni][ks] = *(const bf16x8*)(BsB + (wcol + ni * 16 + fr) * 128 + ks * 64 + fg * 16);
#pragma unroll
        for (int mi = 0; mi < MR; ++mi)
#pragma unroll
            for (int ni = 0; ni < 4; ++ni)
#pragma unroll
                for (int ks = 0; ks < 2; ++ks)
                    acc[mi][ni] = __builtin_amdgcn_mfma_f32_16x16x32_bf16(af[mi][ks], bfr[ni][ks], acc[mi][ni], 0, 0, 0);
    };

    constexpr int NT = K / 64;            // even (12 or 48)
    stage(0, 0);
    __syncthreads();
#pragma unroll 1
    for (int kb = 0; kb < NT; kb += 2) {
        stage(kb + 1, 1);                 // issue next-tile loads BEFORE compute
        compute(0);
        __syncthreads();                  // vmcnt(0) drains the overlapped stage
        if (kb + 2 < NT) stage(kb + 2, 0);
        compute(1);
        __syncthreads();
    }

    // ---- epilogue ----
    float bv[4];
#pragma unroll
    for (int ni = 0; ni < 4; ++ni)
        bv[ni] = bias[e * NC + n0 + wcol + ni * 16 + fr];
#pragma unroll
    for (int mi = 0; mi < MR; ++mi) {
#pragma unroll
        for (int r = 0; r < 4; ++r) {
            int gi = m0 + wrow + mi * 16 + fg * 4 + r;
            if (gi < ce) {
                if constexpr (STAGE1) {
                    size_t orow = (size_t)(bH + gi);
#pragma unroll
                    for (int ni = 0; ni < 4; ++ni) {
                        int col = n0 + wcol + ni * 16 + fr;
                        float v = gelu_tanh(acc[mi][ni][r] + bv[ni]);
                        ((ushort_t*)outp)[orow * NC + col] =
                            __builtin_bit_cast(ushort_t, (__bf16)v);
                    }
                } else {
                    size_t orow = (size_t)slot[e * TOKENS + gi];
#pragma unroll
                    for (int ni = 0; ni < 4; ++ni) {
                        int col = n0 + wcol + ni * 16 + fr;
                        ((float*)outp)[orow * NC + col] = acc[mi][ni][r] + bv[ni];
                    }
                }
            }
        }
    }
}

// ---------------- weighted 2-slot combine + LayerNorm, wave per token ----------------
__global__ void k_ln(const float* __restrict__ Y, const float* __restrict__ wslot,
                     const float* __restrict__ g, const float* __restrict__ b,
                     float* __restrict__ out) {
    int wv = threadIdx.x >> 6, lane = threadIdx.x & 63;
    int t = blockIdx.x * 4 + wv;
    const float* y0 = Y + (size_t)(2 * t) * DMODEL;
    const float* y1 = y0 + DMODEL;
    float w0 = wslot[2 * t], w1 = wslot[2 * t + 1];
    float4 v[3];
    float s = 0.f, ss = 0.f;
#pragma unroll
    for (int j = 0; j < 3; ++j) {
        int base = (j * 64 + lane) * 4;
        float4 a0 = *(const float4*)(y0 + base);
        float4 a1 = *(const float4*)(y1 + base);
        float4 c;
        c.x = w0 * a0.x + w1 * a1.x;
        c.y = w0 * a0.y + w1 * a1.y;
        c.z = w0 * a0.z + w1 * a1.z;
        c.w = w0 * a0.w + w1 * a1.w;
        v[j] = c;
        s  += c.x + c.y + c.z + c.w;
        ss += c.x * c.x + c.y * c.y + c.z * c.z + c.w * c.w;
    }
#pragma unroll
    for (int o = 32; o > 0; o >>= 1) { s += __shfl_xor(s, o); ss += __shfl_xor(ss, o); }
    float mu = s * (1.f / 768.f);
    float var = ss * (1.f / 768.f) - mu * mu;
    float inv = rsqrtf(var + 1e-5f);
    float* row = out + (size_t)t * DMODEL;
#pragma unroll
    for (int j = 0; j < 3; ++j) {
        int base = (j * 64 + lane) * 4;
        float4 gv = *(const float4*)(g + base);
        float4 bv = *(const float4*)(b + base);
        float4 o4;
        o4.x = (v[j].x - mu) * inv * gv.x + bv.x;
        o4.y = (v[j].y - mu) * inv * gv.y + bv.y;
        o4.z = (v[j].z - mu) * inv * gv.z + bv.z;
        o4.w = (v[j].w - mu) * inv * gv.w + bv.w;
        *(float4*)(row + base) = o4;
    }
}

extern "C" void kernel_launch(void* const* d_in, const int* in_sizes, int n_in,
                              void* d_out, int out_size, void* d_ws, size_t ws_size,
                              hipStream_t stream) {
    const float* x    = (const float*)d_in[0];
    const float* Wr   = (const float*)d_in[1];
    const float* br   = (const float*)d_in[2];
    const float* W1   = (const float*)d_in[3];
    const float* b1   = (const float*)d_in[4];
    const float* W2   = (const float*)d_in[5];
    const float* b2   = (const float*)d_in[6];
    const float* ln_g = (const float*)d_in[7];
    const float* ln_b = (const float*)d_in[8];
    float* out = (float*)d_out;

    char* ws = (char*)d_ws;
    int*      cnt   = (int*)(ws + 0);                    //    32 B
    int*      sch   = (int*)(ws + 64);                   //     1 KB
    int*      tok   = (int*)(ws + 4096);                 //   128 KB
    int*      slot  = (int*)(ws + 135168);               //   128 KB
    float*    wslot = (float*)(ws + 266240);             //    32 KB
    ushort_t* xb    = (ushort_t*)(ws + 327680);          //  6.29 MB
    ushort_t* W1t   = (ushort_t*)(ws + 6619136);         // 37.75 MB  [e][h][d]
    ushort_t* W2t   = (ushort_t*)(ws + 44367872);        // 37.75 MB  [e][o][h]
    ushort_t* H     = (ushort_t*)(ws + 82116608);        // 50.33 MB  [8192][3072] bf16, packed
    float*    Y     = (float*)(ws + 132448256);          // 25.17 MB  [8192][768] f32, slot-indexed

    hipMemsetAsync(cnt, 0, 32, stream);

    k_transpose_cvt<<<dim3(DHID / 32, DMODEL / 32, NEXP), dim3(256), 0, stream>>>(W1, W1t, DMODEL, DHID);
    k_transpose_cvt<<<dim3(DMODEL / 32, DHID / 32, NEXP), dim3(256), 0, stream>>>(W2, W2t, DHID, DMODEL);
    k_router<<<dim3(TOKENS / 4), dim3(256), 0, stream>>>(x, Wr, br, cnt, tok, slot, wslot, xb);
    k_sched<<<dim3(1), dim3(64), 0, stream>>>(cnt, sch);

    // stage A: H[baseH[e]+gi] = gelu(X[tok] @ W1t^T + b1)   [K=768, NC=3072]
    k_gemm<128, DMODEL, DHID, true><<<dim3(MAXTA, DHID / 128), dim3(256), 0, stream>>>(
        xb, tok, slot, W1t, b1, H, cnt, sch);
    // stage B: Y[slot] = H @ W2t^T + b2                     [K=3072, NC=768]
    k_gemm<64, DHID, DMODEL, false><<<dim3(MAXTB, DMODEL / 128), dim3(256), 0, stream>>>(
        H, tok, slot, W2t, b2, Y, cnt, sch);

    k_ln<<<dim3(TOKENS / 4), dim3(256), 0, stream>>>(Y, wslot, ln_g, ln_b, out);
}

// Round 4
// 321.385 us; speedup vs baseline: 3.5516x; 1.1615x over previous
//
#include <hip/hip_runtime.h>
#include <hip/hip_bf16.h>

#define TOKENS 4096
#define DMODEL 768
#define DHID   3072
#define NEXP   8
#define MAXTA  72     // sum ceil(ce/128) <= 8192/128+7 = 71
#define MAXTB  40     // sum ceil(ce/256) <= 8192/256+7 = 39

typedef __bf16 bf16x8 __attribute__((ext_vector_type(8)));
typedef float  f32x4  __attribute__((ext_vector_type(4)));
typedef unsigned short ushort_t;

#define VMCNT(n) asm volatile("s_waitcnt vmcnt(" #n ")" ::: "memory")

__device__ __forceinline__ void wg_barrier() {
    asm volatile("" ::: "memory");
    __builtin_amdgcn_s_barrier();
    asm volatile("" ::: "memory");
}

__device__ __forceinline__ float gelu_tanh(float x) {
    // jax.nn.gelu default (approximate=True)
    float z = 0.7978845608028654f * (x + 0.044715f * x * x * x);
    float t = 1.0f - 2.0f / (__expf(2.0f * z) + 1.0f);
    return 0.5f * x * (1.0f + t);
}

__device__ __forceinline__ float bf2f(ushort_t u) {
    unsigned v = ((unsigned)u) << 16;
    return __builtin_bit_cast(float, v);
}

__device__ __forceinline__ void gload16(const void* g, void* l) {
    __builtin_amdgcn_global_load_lds((const __attribute__((address_space(1))) void*)g,
                                     (__attribute__((address_space(3))) void*)l, 16, 0, 0);
}

// ---------------- batched transpose + convert: in fp32 [R][C] -> out bf16 [C][R] ----------------
__global__ void k_transpose_cvt(const float* __restrict__ in, ushort_t* __restrict__ out,
                                int R, int C) {
    __shared__ float tile[32][33];
    int bx = blockIdx.x, by = blockIdx.y, bz = blockIdx.z;
    int tx = threadIdx.x & 31, ty = threadIdx.x >> 5;   // 32 x 8
    const float* ip = in + (size_t)bz * R * C;
    ushort_t* op = out + (size_t)bz * R * C;
#pragma unroll
    for (int i = 0; i < 4; ++i) {
        int r = by * 32 + ty + i * 8;
        int c = bx * 32 + tx;
        tile[ty + i * 8][tx] = ip[(size_t)r * C + c];
    }
    __syncthreads();
#pragma unroll
    for (int i = 0; i < 4; ++i) {
        int c = bx * 32 + ty + i * 8;   // output row (C index)
        int r = by * 32 + tx;           // output col (R index)
        float f = tile[tx][ty + i * 8];
        op[(size_t)c * R + r] = __builtin_bit_cast(ushort_t, (__bf16)f);
    }
}

// ---------------- router: fp32 logits + top-2, fused x->bf16 cast ----------------
__global__ void k_router(const float* __restrict__ x, const float* __restrict__ Wr,
                         const float* __restrict__ br, int* __restrict__ cnt,
                         int* __restrict__ tok, int* __restrict__ slot,
                         float* __restrict__ wslot, ushort_t* __restrict__ xb) {
    int wv = threadIdx.x >> 6;
    int lane = threadIdx.x & 63;
    int t = blockIdx.x * 4 + wv;
    const float* xr = x + (size_t)t * DMODEL;
    float4 xv[3];
#pragma unroll
    for (int j = 0; j < 3; ++j) xv[j] = *(const float4*)(xr + (j * 64 + lane) * 4);
#pragma unroll
    for (int j = 0; j < 3; ++j) {
        int base = (j * 64 + lane) * 4;
        ushort4 o;
        o.x = __builtin_bit_cast(ushort_t, (__bf16)xv[j].x);
        o.y = __builtin_bit_cast(ushort_t, (__bf16)xv[j].y);
        o.z = __builtin_bit_cast(ushort_t, (__bf16)xv[j].z);
        o.w = __builtin_bit_cast(ushort_t, (__bf16)xv[j].w);
        *(ushort4*)(xb + (size_t)t * DMODEL + base) = o;
    }
    float lg[8];
#pragma unroll
    for (int e = 0; e < 8; ++e) {
        float s = 0.f;
#pragma unroll
        for (int j = 0; j < 3; ++j) {
            int base = (j * 64 + lane) * 4;
            s += xv[j].x * Wr[(base + 0) * 8 + e];
            s += xv[j].y * Wr[(base + 1) * 8 + e];
            s += xv[j].z * Wr[(base + 2) * 8 + e];
            s += xv[j].w * Wr[(base + 3) * 8 + e];
        }
#pragma unroll
        for (int o = 32; o > 0; o >>= 1) s += __shfl_xor(s, o);
        lg[e] = s + br[e];
    }
    if (lane == 0) {
        int e0 = 0; float b0 = lg[0];
#pragma unroll
        for (int e = 1; e < 8; ++e) if (lg[e] > b0) { b0 = lg[e]; e0 = e; }
        int e1 = -1; float b1v = -1e30f;
#pragma unroll
        for (int e = 0; e < 8; ++e) if (e != e0 && lg[e] > b1v) { b1v = lg[e]; e1 = e; }
        float w0 = 1.f / (1.f + __expf(b1v - b0));   // renormalized top-2 softmax
        float w1 = 1.f - w0;
        int p0 = atomicAdd(&cnt[e0], 1);
        tok[e0 * TOKENS + p0] = t; slot[e0 * TOKENS + p0] = 2 * t;
        int p1 = atomicAdd(&cnt[e1], 1);
        tok[e1 * TOKENS + p1] = t; slot[e1 * TOKENS + p1] = 2 * t + 1;
        wslot[2 * t] = w0; wslot[2 * t + 1] = w1;
    }
}

// ---------------- tile scheduler ----------------
// sch[0]=nA(BM=128), sch[1]=nB(BM=256), sch[2..9]=baseH prefix,
// sch[16..87]=A tiles (e<<20|m0), sch[96..135]=B tiles
__global__ void k_sched(const int* __restrict__ cnt, int* __restrict__ sch) {
    if (threadIdx.x == 0) {
        int base = 0, na = 0, nb = 0;
        for (int e = 0; e < NEXP; ++e) {
            sch[2 + e] = base;
            int ce = cnt[e];
            for (int m = 0; m < ce; m += 128) sch[16 + na++] = (e << 20) | m;
            for (int m = 0; m < ce; m += 256) sch[96 + nb++] = (e << 20) | m;
            base += ce;
        }
        sch[0] = na;
        sch[1] = nb;
    }
}

// ---------------- counted-vmcnt phased GEMM, triple-buffered, swizzled LDS ----------------
// 8 waves, wave-tile 64x64. BM+BN == 384 (LDS 3*48KB = 144KB).
// STAGE1: A rows gathered via tok[], epilogue gelu -> H bf16 packed.
// else:   A rows packed H (+ kbase k-offset, split-K via blockIdx.z),
//         epilogue (+bias if z==0) -> Y2 bf16, rows scattered via slot[].
template<int BM, int BN, int WN, bool STAGE1>
__launch_bounds__(512)
__global__ void k_gemm8(const ushort_t* __restrict__ Abase, const int* __restrict__ tok,
                        const int* __restrict__ slot, const ushort_t* __restrict__ Wb,
                        const float* __restrict__ bias, void* __restrict__ outp,
                        const int* __restrict__ cnt, const int* __restrict__ sch) {
    constexpr int KR  = STAGE1 ? DMODEL : DHID;      // row stride of A and W sources
    constexpr int NCn = STAGE1 ? DHID : DMODEL;      // total N per expert
    constexpr int NT  = STAGE1 ? (DMODEL / 64) : (DHID / 2 / 64);  // 12 or 24 K-tiles
    constexpr int BUFB = (BM + BN) * 128;            // bytes per buffer (49152)

    // bijective XCD swizzle (m204) on tile index
    const int gx = gridDim.x;
    const int bx = blockIdx.x;
    const int q = gx >> 3, r = gx & 7;
    const int xcd = bx & 7;
    const int tile = (xcd < r ? xcd * (q + 1) : r * (q + 1) + (xcd - r) * q) + (bx >> 3);

    const int nT = sch[STAGE1 ? 0 : 1];
    if (tile >= nT) return;
    const int ent = sch[(STAGE1 ? 16 : 96) + tile];
    const int e = ent >> 20, m0 = ent & 0xFFFFF;
    const int ce = cnt[e];
    const int bH = sch[2 + e];
    const int n0 = blockIdx.y * BN;
    const int kbase = STAGE1 ? 0 : (int)blockIdx.z * (DHID / 2);

    __shared__ ushort_t lds[3 * (BM + BN) * 64];
    char* ldsB = (char*)lds;

    const int tid = threadIdx.x, lane = tid & 63, w = tid >> 6;
    const int wm = w / WN, wn = w % WN;
    const int wmBase = wm * 64, wnBase = wn * 64;
    const int fr = lane & 15, fg = lane >> 4;

    // per-lane inverse-swizzled global sources for the 6 8KB chunks
    const ushort_t* src[6];
#pragma unroll
    for (int c = 0; c < 6; ++c) {
        int o = c * 8192 + tid * 16;                 // buffer-relative linear byte
        bool isA = o < BM * 128;
        int po = isA ? o : (o - BM * 128);
        int so = po ^ (((po >> 9) & 1) << 5);        // involution
        int rrow = so >> 7, cb = so & 127;
        if (isA) {
            int gi = min(m0 + rrow, ce - 1);
            size_t arow = STAGE1 ? (size_t)tok[e * TOKENS + gi] : (size_t)(bH + gi);
            src[c] = Abase + arow * KR + kbase + (cb >> 1);
        } else {
            src[c] = Wb + ((size_t)e * NCn + n0 + rrow) * KR + kbase + (cb >> 1);
        }
    }

    auto issue3 = [&](int kt, int half) {
        char* db = ldsB + (kt % 3) * BUFB;
#pragma unroll
        for (int c = 0; c < 3; ++c) {
            int cc = half * 3 + c;
            gload16(src[cc] + kt * 64, db + cc * 8192 + w * 1024);
        }
    };
    auto loadfrag = [&](int kt, int ks, bf16x8* af, bf16x8* bf) {
        const char* ab = ldsB + (kt % 3) * BUFB;
        const char* bb = ab + BM * 128;
#pragma unroll
        for (int i = 0; i < 4; ++i) {
            int oA = (wmBase + i * 16 + fr) * 128 + ks * 64 + fg * 16;
            af[i] = *(const bf16x8*)(ab + (oA ^ (((oA >> 9) & 1) << 5)));
            int oB = (wnBase + i * 16 + fr) * 128 + ks * 64 + fg * 16;
            bf[i] = *(const bf16x8*)(bb + (oB ^ (((oB >> 9) & 1) << 5)));
        }
    };

    f32x4 acc[4][4] = {};

    // prologue: tiles 0 and 1 in flight; wait tile 0
    issue3(0, 0); issue3(0, 1);
    issue3(1, 0); issue3(1, 1);
    VMCNT(6);
    wg_barrier();

#pragma unroll 1
    for (int kt = 0; kt < NT; ++kt) {
        // ---- phase 1: ks=0 ----
        {
            bf16x8 a0[4], b0[4];
            loadfrag(kt, 0, a0, b0);
            if (kt + 2 < NT) issue3(kt + 2, 0);
            wg_barrier();
            __builtin_amdgcn_s_setprio(1);
#pragma unroll
            for (int mi = 0; mi < 4; ++mi)
#pragma unroll
                for (int ni = 0; ni < 4; ++ni)
                    acc[mi][ni] = __builtin_amdgcn_mfma_f32_16x16x32_bf16(a0[mi], b0[ni], acc[mi][ni], 0, 0, 0);
            __builtin_amdgcn_s_setprio(0);
            wg_barrier();
        }
        // ---- phase 2: ks=1 ----
        {
            bf16x8 a1[4], b1f[4];
            loadfrag(kt, 1, a1, b1f);
            if (kt + 2 < NT) { issue3(kt + 2, 1); VMCNT(6); }
            else             { VMCNT(0); }
            wg_barrier();
            __builtin_amdgcn_s_setprio(1);
#pragma unroll
            for (int mi = 0; mi < 4; ++mi)
#pragma unroll
                for (int ni = 0; ni < 4; ++ni)
                    acc[mi][ni] = __builtin_amdgcn_mfma_f32_16x16x32_bf16(a1[mi], b1f[ni], acc[mi][ni], 0, 0, 0);
            __builtin_amdgcn_s_setprio(0);
            wg_barrier();
        }
    }

    // ---- epilogue ----
    float bv[4];
#pragma unroll
    for (int ni = 0; ni < 4; ++ni)
        bv[ni] = bias[e * NCn + n0 + wnBase + ni * 16 + fr];
#pragma unroll
    for (int mi = 0; mi < 4; ++mi) {
#pragma unroll
        for (int r4 = 0; r4 < 4; ++r4) {
            int gi = m0 + wmBase + mi * 16 + fg * 4 + r4;
            if (gi < ce) {
                if constexpr (STAGE1) {
                    size_t orow = (size_t)(bH + gi);
#pragma unroll
                    for (int ni = 0; ni < 4; ++ni) {
                        int col = n0 + wnBase + ni * 16 + fr;
                        float v = gelu_tanh(acc[mi][ni][r4] + bv[ni]);
                        ((ushort_t*)outp)[orow * DHID + col] =
                            __builtin_bit_cast(ushort_t, (__bf16)v);
                    }
                } else {
                    size_t orow = (size_t)blockIdx.z * 8192 + (size_t)slot[e * TOKENS + gi];
                    float badd = (blockIdx.z == 0) ? 1.f : 0.f;
#pragma unroll
                    for (int ni = 0; ni < 4; ++ni) {
                        int col = n0 + wnBase + ni * 16 + fr;
                        float v = acc[mi][ni][r4] + badd * bv[ni];
                        ((ushort_t*)outp)[orow * DMODEL + col] =
                            __builtin_bit_cast(ushort_t, (__bf16)v);
                    }
                }
            }
        }
    }
}

// ---------------- combine 2 slots x 2 split-K halves (bf16) + LayerNorm ----------------
__global__ void k_ln(const ushort_t* __restrict__ Y2, const float* __restrict__ wslot,
                     const float* __restrict__ g, const float* __restrict__ b,
                     float* __restrict__ out) {
    int wv = threadIdx.x >> 6, lane = threadIdx.x & 63;
    int t = blockIdx.x * 4 + wv;
    const ushort_t* r00 = Y2 + (size_t)(2 * t) * DMODEL;            // slot0, half0
    const ushort_t* r01 = Y2 + (size_t)(8192 + 2 * t) * DMODEL;     // slot0, half1
    const ushort_t* r10 = r00 + DMODEL;                              // slot1, half0
    const ushort_t* r11 = r01 + DMODEL;                              // slot1, half1
    float w0 = wslot[2 * t], w1 = wslot[2 * t + 1];
    float4 v[3];
    float s = 0.f, ss = 0.f;
#pragma unroll
    for (int j = 0; j < 3; ++j) {
        int base = (j * 64 + lane) * 4;
        ushort4 a0 = *(const ushort4*)(r00 + base);
        ushort4 a1 = *(const ushort4*)(r01 + base);
        ushort4 c0 = *(const ushort4*)(r10 + base);
        ushort4 c1 = *(const ushort4*)(r11 + base);
        float4 c;
        c.x = w0 * (bf2f(a0.x) + bf2f(a1.x)) + w1 * (bf2f(c0.x) + bf2f(c1.x));
        c.y = w0 * (bf2f(a0.y) + bf2f(a1.y)) + w1 * (bf2f(c0.y) + bf2f(c1.y));
        c.z = w0 * (bf2f(a0.z) + bf2f(a1.z)) + w1 * (bf2f(c0.z) + bf2f(c1.z));
        c.w = w0 * (bf2f(a0.w) + bf2f(a1.w)) + w1 * (bf2f(c0.w) + bf2f(c1.w));
        v[j] = c;
        s  += c.x + c.y + c.z + c.w;
        ss += c.x * c.x + c.y * c.y + c.z * c.z + c.w * c.w;
    }
#pragma unroll
    for (int o = 32; o > 0; o >>= 1) { s += __shfl_xor(s, o); ss += __shfl_xor(ss, o); }
    float mu = s * (1.f / 768.f);
    float var = ss * (1.f / 768.f) - mu * mu;
    float inv = rsqrtf(var + 1e-5f);
    float* row = out + (size_t)t * DMODEL;
#pragma unroll
    for (int j = 0; j < 3; ++j) {
        int base = (j * 64 + lane) * 4;
        float4 gv = *(const float4*)(g + base);
        float4 bv = *(const float4*)(b + base);
        float4 o4;
        o4.x = (v[j].x - mu) * inv * gv.x + bv.x;
        o4.y = (v[j].y - mu) * inv * gv.y + bv.y;
        o4.z = (v[j].z - mu) * inv * gv.z + bv.z;
        o4.w = (v[j].w - mu) * inv * gv.w + bv.w;
        *(float4*)(row + base) = o4;
    }
}

extern "C" void kernel_launch(void* const* d_in, const int* in_sizes, int n_in,
                              void* d_out, int out_size, void* d_ws, size_t ws_size,
                              hipStream_t stream) {
    const float* x    = (const float*)d_in[0];
    const float* Wr   = (const float*)d_in[1];
    const float* br   = (const float*)d_in[2];
    const float* W1   = (const float*)d_in[3];
    const float* b1   = (const float*)d_in[4];
    const float* W2   = (const float*)d_in[5];
    const float* b2   = (const float*)d_in[6];
    const float* ln_g = (const float*)d_in[7];
    const float* ln_b = (const float*)d_in[8];
    float* out = (float*)d_out;

    char* ws = (char*)d_ws;
    int*      cnt   = (int*)(ws + 0);                    //    32 B
    int*      sch   = (int*)(ws + 64);                   //   ~1 KB
    int*      tok   = (int*)(ws + 4096);                 //   128 KB
    int*      slot  = (int*)(ws + 135168);               //   128 KB
    float*    wslot = (float*)(ws + 266240);             //    32 KB
    ushort_t* xb    = (ushort_t*)(ws + 327680);          //  6.29 MB
    ushort_t* W1t   = (ushort_t*)(ws + 6619136);         // 37.75 MB  [e][h][d]
    ushort_t* W2t   = (ushort_t*)(ws + 44367872);        // 37.75 MB  [e][o][h]
    ushort_t* H     = (ushort_t*)(ws + 82116608);        // 50.33 MB  [8192][3072] bf16, packed
    ushort_t* Y2    = (ushort_t*)(ws + 132448256);       // 25.17 MB  [2][8192][768] bf16

    hipMemsetAsync(cnt, 0, 32, stream);

    k_transpose_cvt<<<dim3(DHID / 32, DMODEL / 32, NEXP), dim3(256), 0, stream>>>(W1, W1t, DMODEL, DHID);
    k_transpose_cvt<<<dim3(DMODEL / 32, DHID / 32, NEXP), dim3(256), 0, stream>>>(W2, W2t, DHID, DMODEL);
    k_router<<<dim3(TOKENS / 4), dim3(256), 0, stream>>>(x, Wr, br, cnt, tok, slot, wslot, xb);
    k_sched<<<dim3(1), dim3(64), 0, stream>>>(cnt, sch);

    // stage A: H[bH+gi] = gelu(X[tok] @ W1t^T + b1)    BM=128 BN=256, K=768
    k_gemm8<128, 256, 4, true><<<dim3(MAXTA, DHID / 256, 1), dim3(512), 0, stream>>>(
        xb, tok, slot, W1t, b1, H, cnt, sch);
    // stage B: Y2[z][slot] = H @ W2t^T (+b2 if z==0)   BM=256 BN=128, split-K 2x1536
    k_gemm8<256, 128, 2, false><<<dim3(MAXTB, DMODEL / 128, 2), dim3(512), 0, stream>>>(
        H, tok, slot, W2t, b2, Y2, cnt, sch);

    k_ln<<<dim3(TOKENS / 4), dim3(256), 0, stream>>>(Y2, wslot, ln_g, ln_b, out);
}

// Round 5
// 237.461 us; speedup vs baseline: 4.8069x; 1.3534x over previous
//
#include <hip/hip_runtime.h>
#include <hip/hip_bf16.h>

#define TOKENS 4096
#define DMODEL 768
#define DHID   3072
#define NEXP   8
#define MAXTA  72     // sum ceil(ce/128) <= 8192/128+7 = 71
#define MAXTB  40     // sum ceil(ce/256) <= 8192/256+7 = 39

typedef __bf16 bf16x8 __attribute__((ext_vector_type(8)));
typedef float  f32x4  __attribute__((ext_vector_type(4)));
typedef unsigned short ushort_t;

#define VMCNT(n) asm volatile("s_waitcnt vmcnt(" #n ")" ::: "memory")

__device__ __forceinline__ void wg_barrier() {
    asm volatile("" ::: "memory");
    __builtin_amdgcn_s_barrier();
    asm volatile("" ::: "memory");
}

__device__ __forceinline__ float gelu_tanh(float x) {
    // jax.nn.gelu default (approximate=True)
    float z = 0.7978845608028654f * (x + 0.044715f * x * x * x);
    float t = 1.0f - 2.0f / (__expf(2.0f * z) + 1.0f);
    return 0.5f * x * (1.0f + t);
}

__device__ __forceinline__ float bf2f(ushort_t u) {
    unsigned v = ((unsigned)u) << 16;
    return __builtin_bit_cast(float, v);
}

__device__ __forceinline__ void gload16(const void* g, void* l) {
    __builtin_amdgcn_global_load_lds((const __attribute__((address_space(1))) void*)g,
                                     (__attribute__((address_space(3))) void*)l, 16, 0, 0);
}

// ---------------- transpose + convert: in fp32 [R][C] -> out bf16 [C][R] ----------------
// 64x64 tile, float4 reads, float4 LDS writes, ushort4 stores (128B/16-lane segs)
__global__ void k_transpose_cvt(const float* __restrict__ in, ushort_t* __restrict__ out,
                                int R, int C) {
    __shared__ float tile[64 * 68];
    const int bx = blockIdx.x, by = blockIdx.y, bz = blockIdx.z;
    const float* ip = in + (size_t)bz * R * C;
    ushort_t* op = out + (size_t)bz * R * C;
    const int tid = threadIdx.x;
    {
        const int cq = tid & 15, rg = tid >> 4;       // 16 x 16
#pragma unroll
        for (int i = 0; i < 4; ++i) {
            int rl = rg + i * 16;
            float4 v = *(const float4*)(ip + (size_t)(by * 64 + rl) * C + bx * 64 + cq * 4);
            *(float4*)(&tile[rl * 68 + cq * 4]) = v;
        }
    }
    __syncthreads();
    {
        const int rq = tid & 15, cg = tid >> 4;
#pragma unroll
        for (int i = 0; i < 4; ++i) {
            int cl = cg + i * 16;
            ushort4 o;
            o.x = __builtin_bit_cast(ushort_t, (__bf16)tile[(rq * 4 + 0) * 68 + cl]);
            o.y = __builtin_bit_cast(ushort_t, (__bf16)tile[(rq * 4 + 1) * 68 + cl]);
            o.z = __builtin_bit_cast(ushort_t, (__bf16)tile[(rq * 4 + 2) * 68 + cl]);
            o.w = __builtin_bit_cast(ushort_t, (__bf16)tile[(rq * 4 + 3) * 68 + cl]);
            *(ushort4*)(op + (size_t)(bx * 64 + cl) * R + by * 64 + rq * 4) = o;
        }
    }
}

// ---------------- router: LDS-transposed Wr, 8 tokens/wave, block-aggregated atomics ----------------
__launch_bounds__(256)
__global__ void k_router(const float* __restrict__ x, const float* __restrict__ Wr,
                         const float* __restrict__ br, int* __restrict__ cnt,
                         int* __restrict__ tok, int* __restrict__ slot,
                         float* __restrict__ wslot, ushort_t* __restrict__ xb) {
    __shared__ float WrT[NEXP * DMODEL];   // [e][d], 24 KB
    __shared__ int   te0[32], te1[32];
    __shared__ float tw0v[32], tw1v[32];
    __shared__ int   lcnt[NEXP], gbase[NEXP];

    const int tid = threadIdx.x;
    const int wv = tid >> 6, lane = tid & 63;

    // stage Wr transposed: Wr flat [d*8+e] -> WrT[e*768+d]
#pragma unroll
    for (int i = 0; i < 6; ++i) {
        int idx4 = i * 256 + tid;                  // float4 index (1536 total)
        float4 v = ((const float4*)Wr)[idx4];
        int flat = idx4 * 4;
        int d = flat >> 3, e0 = flat & 7;          // e0 in {0,4}
        WrT[(e0 + 0) * DMODEL + d] = v.x;
        WrT[(e0 + 1) * DMODEL + d] = v.y;
        WrT[(e0 + 2) * DMODEL + d] = v.z;
        WrT[(e0 + 3) * DMODEL + d] = v.w;
    }
    if (tid < NEXP) lcnt[tid] = 0;
    float brv[8];
#pragma unroll
    for (int e = 0; e < 8; ++e) brv[e] = br[e];
    __syncthreads();

#pragma unroll 1
    for (int it = 0; it < 8; ++it) {
        int t = blockIdx.x * 32 + wv * 8 + it;
        const float* xr = x + (size_t)t * DMODEL;
        float4 xv[3];
#pragma unroll
        for (int j = 0; j < 3; ++j) xv[j] = *(const float4*)(xr + (j * 64 + lane) * 4);
#pragma unroll
        for (int j = 0; j < 3; ++j) {
            int base = (j * 64 + lane) * 4;
            ushort4 o;
            o.x = __builtin_bit_cast(ushort_t, (__bf16)xv[j].x);
            o.y = __builtin_bit_cast(ushort_t, (__bf16)xv[j].y);
            o.z = __builtin_bit_cast(ushort_t, (__bf16)xv[j].z);
            o.w = __builtin_bit_cast(ushort_t, (__bf16)xv[j].w);
            *(ushort4*)(xb + (size_t)t * DMODEL + base) = o;
        }
        float lg[8];
#pragma unroll
        for (int e = 0; e < 8; ++e) {
            float s = 0.f;
#pragma unroll
            for (int j = 0; j < 3; ++j) {
                const float4 wv4 = *(const float4*)(&WrT[e * DMODEL + (j * 64 + lane) * 4]);
                s += xv[j].x * wv4.x;
                s += xv[j].y * wv4.y;
                s += xv[j].z * wv4.z;
                s += xv[j].w * wv4.w;
            }
#pragma unroll
            for (int o = 32; o > 0; o >>= 1) s += __shfl_xor(s, o);
            lg[e] = s + brv[e];
        }
        if (lane == 0) {
            int e0 = 0; float b0 = lg[0];
#pragma unroll
            for (int e = 1; e < 8; ++e) if (lg[e] > b0) { b0 = lg[e]; e0 = e; }
            int e1 = -1; float b1v = -1e30f;
#pragma unroll
            for (int e = 0; e < 8; ++e) if (e != e0 && lg[e] > b1v) { b1v = lg[e]; e1 = e; }
            float w0 = 1.f / (1.f + __expf(b1v - b0));   // renormalized top-2 softmax
            float w1 = 1.f - w0;
            int lt = wv * 8 + it;
            te0[lt] = e0; te1[lt] = e1; tw0v[lt] = w0; tw1v[lt] = w1;
            wslot[2 * t] = w0; wslot[2 * t + 1] = w1;
        }
    }
    __syncthreads();

    int myE = 0, myPos = 0, myTok = 0, myK = 0;
    if (tid < 64) {
        int lt = tid >> 1; myK = tid & 1;
        myE = myK ? te1[lt] : te0[lt];
        myTok = blockIdx.x * 32 + lt;
        myPos = atomicAdd(&lcnt[myE], 1);
    }
    __syncthreads();
    if (tid < NEXP) gbase[tid] = atomicAdd(&cnt[tid], lcnt[tid]);
    __syncthreads();
    if (tid < 64) {
        int g = gbase[myE] + myPos;
        tok[myE * TOKENS + g] = myTok;
        slot[myE * TOKENS + g] = 2 * myTok + myK;
    }
}

// ---------------- tile scheduler ----------------
// sch[0]=nA(BM=128), sch[1]=nB(BM=256), sch[2..9]=baseH prefix,
// sch[16..87]=A tiles (e<<20|m0), sch[96..135]=B tiles
__global__ void k_sched(const int* __restrict__ cnt, int* __restrict__ sch) {
    if (threadIdx.x == 0) {
        int base = 0, na = 0, nb = 0;
        for (int e = 0; e < NEXP; ++e) {
            sch[2 + e] = base;
            int ce = cnt[e];
            for (int m = 0; m < ce; m += 128) sch[16 + na++] = (e << 20) | m;
            for (int m = 0; m < ce; m += 256) sch[96 + nb++] = (e << 20) | m;
            base += ce;
        }
        sch[0] = na;
        sch[1] = nb;
    }
}

// ---------------- counted-vmcnt phased GEMM, triple-buffered, swizzled LDS ----------------
// 8 waves, wave-tile 64x64. BM+BN == 384 (LDS 3*48KB = 144KB).
template<int BM, int BN, int WN, bool STAGE1>
__launch_bounds__(512)
__global__ void k_gemm8(const ushort_t* __restrict__ Abase, const int* __restrict__ tok,
                        const int* __restrict__ slot, const ushort_t* __restrict__ Wb,
                        const float* __restrict__ bias, void* __restrict__ outp,
                        const int* __restrict__ cnt, const int* __restrict__ sch) {
    constexpr int KR  = STAGE1 ? DMODEL : DHID;
    constexpr int NCn = STAGE1 ? DHID : DMODEL;
    constexpr int NT  = STAGE1 ? (DMODEL / 64) : (DHID / 2 / 64);  // 12 or 24
    constexpr int BUFB = (BM + BN) * 128;

    const int gx = gridDim.x;
    const int bx = blockIdx.x;
    const int q = gx >> 3, r = gx & 7;
    const int xcd = bx & 7;
    const int tile = (xcd < r ? xcd * (q + 1) : r * (q + 1) + (xcd - r) * q) + (bx >> 3);

    const int nT = sch[STAGE1 ? 0 : 1];
    if (tile >= nT) return;
    const int ent = sch[(STAGE1 ? 16 : 96) + tile];
    const int e = ent >> 20, m0 = ent & 0xFFFFF;
    const int ce = cnt[e];
    const int bH = sch[2 + e];
    const int n0 = blockIdx.y * BN;
    const int kbase = STAGE1 ? 0 : (int)blockIdx.z * (DHID / 2);

    __shared__ ushort_t lds[3 * (BM + BN) * 64];
    char* ldsB = (char*)lds;

    const int tid = threadIdx.x, lane = tid & 63, w = tid >> 6;
    const int wm = w / WN, wn = w % WN;
    const int wmBase = wm * 64, wnBase = wn * 64;
    const int fr = lane & 15, fg = lane >> 4;

    const ushort_t* src[6];
#pragma unroll
    for (int c = 0; c < 6; ++c) {
        int o = c * 8192 + tid * 16;
        bool isA = o < BM * 128;
        int po = isA ? o : (o - BM * 128);
        int so = po ^ (((po >> 9) & 1) << 5);
        int rrow = so >> 7, cb = so & 127;
        if (isA) {
            int gi = min(m0 + rrow, ce - 1);
            size_t arow = STAGE1 ? (size_t)tok[e * TOKENS + gi] : (size_t)(bH + gi);
            src[c] = Abase + arow * KR + kbase + (cb >> 1);
        } else {
            src[c] = Wb + ((size_t)e * NCn + n0 + rrow) * KR + kbase + (cb >> 1);
        }
    }

    auto issue3 = [&](int kt, int half) {
        char* db = ldsB + (kt % 3) * BUFB;
#pragma unroll
        for (int c = 0; c < 3; ++c) {
            int cc = half * 3 + c;
            gload16(src[cc] + kt * 64, db + cc * 8192 + w * 1024);
        }
    };
    auto loadfrag = [&](int kt, int ks, bf16x8* af, bf16x8* bf) {
        const char* ab = ldsB + (kt % 3) * BUFB;
        const char* bb = ab + BM * 128;
#pragma unroll
        for (int i = 0; i < 4; ++i) {
            int oA = (wmBase + i * 16 + fr) * 128 + ks * 64 + fg * 16;
            af[i] = *(const bf16x8*)(ab + (oA ^ (((oA >> 9) & 1) << 5)));
            int oB = (wnBase + i * 16 + fr) * 128 + ks * 64 + fg * 16;
            bf[i] = *(const bf16x8*)(bb + (oB ^ (((oB >> 9) & 1) << 5)));
        }
    };

    f32x4 acc[4][4] = {};

    issue3(0, 0); issue3(0, 1);
    issue3(1, 0); issue3(1, 1);
    VMCNT(6);
    wg_barrier();

#pragma unroll 1
    for (int kt = 0; kt < NT; ++kt) {
        {
            bf16x8 a0[4], b0[4];
            loadfrag(kt, 0, a0, b0);
            if (kt + 2 < NT) issue3(kt + 2, 0);
            wg_barrier();
            __builtin_amdgcn_s_setprio(1);
#pragma unroll
            for (int mi = 0; mi < 4; ++mi)
#pragma unroll
                for (int ni = 0; ni < 4; ++ni)
                    acc[mi][ni] = __builtin_amdgcn_mfma_f32_16x16x32_bf16(a0[mi], b0[ni], acc[mi][ni], 0, 0, 0);
            __builtin_amdgcn_s_setprio(0);
            wg_barrier();
        }
        {
            bf16x8 a1[4], b1f[4];
            loadfrag(kt, 1, a1, b1f);
            if (kt + 2 < NT) { issue3(kt + 2, 1); VMCNT(6); }
            else             { VMCNT(0); }
            wg_barrier();
            __builtin_amdgcn_s_setprio(1);
#pragma unroll
            for (int mi = 0; mi < 4; ++mi)
#pragma unroll
                for (int ni = 0; ni < 4; ++ni)
                    acc[mi][ni] = __builtin_amdgcn_mfma_f32_16x16x32_bf16(a1[mi], b1f[ni], acc[mi][ni], 0, 0, 0);
            __builtin_amdgcn_s_setprio(0);
            wg_barrier();
        }
    }

    float bv[4];
#pragma unroll
    for (int ni = 0; ni < 4; ++ni)
        bv[ni] = bias[e * NCn + n0 + wnBase + ni * 16 + fr];
#pragma unroll
    for (int mi = 0; mi < 4; ++mi) {
#pragma unroll
        for (int r4 = 0; r4 < 4; ++r4) {
            int gi = m0 + wmBase + mi * 16 + fg * 4 + r4;
            if (gi < ce) {
                if constexpr (STAGE1) {
                    size_t orow = (size_t)(bH + gi);
#pragma unroll
                    for (int ni = 0; ni < 4; ++ni) {
                        int col = n0 + wnBase + ni * 16 + fr;
                        float v = gelu_tanh(acc[mi][ni][r4] + bv[ni]);
                        ((ushort_t*)outp)[orow * DHID + col] =
                            __builtin_bit_cast(ushort_t, (__bf16)v);
                    }
                } else {
                    size_t orow = (size_t)blockIdx.z * 8192 + (size_t)slot[e * TOKENS + gi];
                    float badd = (blockIdx.z == 0) ? 1.f : 0.f;
#pragma unroll
                    for (int ni = 0; ni < 4; ++ni) {
                        int col = n0 + wnBase + ni * 16 + fr;
                        float v = acc[mi][ni][r4] + badd * bv[ni];
                        ((ushort_t*)outp)[orow * DMODEL + col] =
                            __builtin_bit_cast(ushort_t, (__bf16)v);
                    }
                }
            }
        }
    }
}

// ---------------- combine 2 slots x 2 split-K halves (bf16) + LayerNorm ----------------
__global__ void k_ln(const ushort_t* __restrict__ Y2, const float* __restrict__ wslot,
                     const float* __restrict__ g, const float* __restrict__ b,
                     float* __restrict__ out) {
    int wv = threadIdx.x >> 6, lane = threadIdx.x & 63;
    int t = blockIdx.x * 4 + wv;
    const ushort_t* r00 = Y2 + (size_t)(2 * t) * DMODEL;
    const ushort_t* r01 = Y2 + (size_t)(8192 + 2 * t) * DMODEL;
    const ushort_t* r10 = r00 + DMODEL;
    const ushort_t* r11 = r01 + DMODEL;
    float w0 = wslot[2 * t], w1 = wslot[2 * t + 1];
    float4 v[3];
    float s = 0.f, ss = 0.f;
#pragma unroll
    for (int j = 0; j < 3; ++j) {
        int base = (j * 64 + lane) * 4;
        ushort4 a0 = *(const ushort4*)(r00 + base);
        ushort4 a1 = *(const ushort4*)(r01 + base);
        ushort4 c0 = *(const ushort4*)(r10 + base);
        ushort4 c1 = *(const ushort4*)(r11 + base);
        float4 c;
        c.x = w0 * (bf2f(a0.x) + bf2f(a1.x)) + w1 * (bf2f(c0.x) + bf2f(c1.x));
        c.y = w0 * (bf2f(a0.y) + bf2f(a1.y)) + w1 * (bf2f(c0.y) + bf2f(c1.y));
        c.z = w0 * (bf2f(a0.z) + bf2f(a1.z)) + w1 * (bf2f(c0.z) + bf2f(c1.z));
        c.w = w0 * (bf2f(a0.w) + bf2f(a1.w)) + w1 * (bf2f(c0.w) + bf2f(c1.w));
        v[j] = c;
        s  += c.x + c.y + c.z + c.w;
        ss += c.x * c.x + c.y * c.y + c.z * c.z + c.w * c.w;
    }
#pragma unroll
    for (int o = 32; o > 0; o >>= 1) { s += __shfl_xor(s, o); ss += __shfl_xor(ss, o); }
    float mu = s * (1.f / 768.f);
    float var = ss * (1.f / 768.f) - mu * mu;
    float inv = rsqrtf(var + 1e-5f);
    float* row = out + (size_t)t * DMODEL;
#pragma unroll
    for (int j = 0; j < 3; ++j) {
        int base = (j * 64 + lane) * 4;
        float4 gv = *(const float4*)(g + base);
        float4 bv = *(const float4*)(b + base);
        float4 o4;
        o4.x = (v[j].x - mu) * inv * gv.x + bv.x;
        o4.y = (v[j].y - mu) * inv * gv.y + bv.y;
        o4.z = (v[j].z - mu) * inv * gv.z + bv.z;
        o4.w = (v[j].w - mu) * inv * gv.w + bv.w;
        *(float4*)(row + base) = o4;
    }
}

extern "C" void kernel_launch(void* const* d_in, const int* in_sizes, int n_in,
                              void* d_out, int out_size, void* d_ws, size_t ws_size,
                              hipStream_t stream) {
    const float* x    = (const float*)d_in[0];
    const float* Wr   = (const float*)d_in[1];
    const float* br   = (const float*)d_in[2];
    const float* W1   = (const float*)d_in[3];
    const float* b1   = (const float*)d_in[4];
    const float* W2   = (const float*)d_in[5];
    const float* b2   = (const float*)d_in[6];
    const float* ln_g = (const float*)d_in[7];
    const float* ln_b = (const float*)d_in[8];
    float* out = (float*)d_out;

    char* ws = (char*)d_ws;
    int*      cnt   = (int*)(ws + 0);                    //    32 B
    int*      sch   = (int*)(ws + 64);                   //   ~1 KB
    int*      tok   = (int*)(ws + 4096);                 //   128 KB
    int*      slot  = (int*)(ws + 135168);               //   128 KB
    float*    wslot = (float*)(ws + 266240);             //    32 KB
    ushort_t* xb    = (ushort_t*)(ws + 327680);          //  6.29 MB
    ushort_t* W1t   = (ushort_t*)(ws + 6619136);         // 37.75 MB  [e][h][d]
    ushort_t* W2t   = (ushort_t*)(ws + 44367872);        // 37.75 MB  [e][o][h]
    ushort_t* H     = (ushort_t*)(ws + 82116608);        // 50.33 MB  [8192][3072] bf16, packed
    ushort_t* Y2    = (ushort_t*)(ws + 132448256);       // 25.17 MB  [2][8192][768] bf16

    hipMemsetAsync(cnt, 0, 32, stream);

    k_transpose_cvt<<<dim3(DHID / 64, DMODEL / 64, NEXP), dim3(256), 0, stream>>>(W1, W1t, DMODEL, DHID);
    k_transpose_cvt<<<dim3(DMODEL / 64, DHID / 64, NEXP), dim3(256), 0, stream>>>(W2, W2t, DHID, DMODEL);
    k_router<<<dim3(TOKENS / 32), dim3(256), 0, stream>>>(x, Wr, br, cnt, tok, slot, wslot, xb);
    k_sched<<<dim3(1), dim3(64), 0, stream>>>(cnt, sch);

    // stage A: H[bH+gi] = gelu(X[tok] @ W1t^T + b1)    BM=128 BN=256, K=768
    k_gemm8<128, 256, 4, true><<<dim3(MAXTA, DHID / 256, 1), dim3(512), 0, stream>>>(
        xb, tok, slot, W1t, b1, H, cnt, sch);
    // stage B: Y2[z][slot] = H @ W2t^T (+b2 if z==0)   BM=256 BN=128, split-K 2x1536
    k_gemm8<256, 128, 2, false><<<dim3(MAXTB, DMODEL / 128, 2), dim3(512), 0, stream>>>(
        H, tok, slot, W2t, b2, Y2, cnt, sch);

    k_ln<<<dim3(TOKENS / 4), dim3(256), 0, stream>>>(Y2, wslot, ln_g, ln_b, out);
}

// Round 6
// 202.282 us; speedup vs baseline: 5.6428x; 1.1739x over previous
//
#include <hip/hip_runtime.h>
#include <hip/hip_bf16.h>

#define TOKENS 4096
#define DMODEL 768
#define DHID   3072
#define NEXP   8
#define MAXT   40     // sum ceil(ce/256) <= 8192/256 + 7 = 39

typedef __bf16 bf16x8 __attribute__((ext_vector_type(8)));
typedef float  f32x4  __attribute__((ext_vector_type(4)));
typedef unsigned short ushort_t;

#define VMCNT(n) asm volatile("s_waitcnt vmcnt(" #n ")" ::: "memory")

__device__ __forceinline__ void wg_barrier() {
    asm volatile("" ::: "memory");
    __builtin_amdgcn_s_barrier();
    asm volatile("" ::: "memory");
}

__device__ __forceinline__ float gelu_tanh(float x) {
    // jax.nn.gelu default (approximate=True)
    float z = 0.7978845608028654f * (x + 0.044715f * x * x * x);
    float t = 1.0f - 2.0f / (__expf(2.0f * z) + 1.0f);
    return 0.5f * x * (1.0f + t);
}

__device__ __forceinline__ float bf2f(ushort_t u) {
    unsigned v = ((unsigned)u) << 16;
    return __builtin_bit_cast(float, v);
}

__device__ __forceinline__ void gload16(const void* g, void* l) {
    __builtin_amdgcn_global_load_lds((const __attribute__((address_space(1))) void*)g,
                                     (__attribute__((address_space(3))) void*)l, 16, 0, 0);
}

// ---------------- transpose + convert: in fp32 [R][C] -> out bf16 [C][R] ----------------
__global__ void k_transpose_cvt(const float* __restrict__ in, ushort_t* __restrict__ out,
                                int R, int C) {
    __shared__ float tile[64 * 68];
    const int bx = blockIdx.x, by = blockIdx.y, bz = blockIdx.z;
    const float* ip = in + (size_t)bz * R * C;
    ushort_t* op = out + (size_t)bz * R * C;
    const int tid = threadIdx.x;
    {
        const int cq = tid & 15, rg = tid >> 4;
#pragma unroll
        for (int i = 0; i < 4; ++i) {
            int rl = rg + i * 16;
            float4 v = *(const float4*)(ip + (size_t)(by * 64 + rl) * C + bx * 64 + cq * 4);
            *(float4*)(&tile[rl * 68 + cq * 4]) = v;
        }
    }
    __syncthreads();
    {
        const int rq = tid & 15, cg = tid >> 4;
#pragma unroll
        for (int i = 0; i < 4; ++i) {
            int cl = cg + i * 16;
            ushort4 o;
            o.x = __builtin_bit_cast(ushort_t, (__bf16)tile[(rq * 4 + 0) * 68 + cl]);
            o.y = __builtin_bit_cast(ushort_t, (__bf16)tile[(rq * 4 + 1) * 68 + cl]);
            o.z = __builtin_bit_cast(ushort_t, (__bf16)tile[(rq * 4 + 2) * 68 + cl]);
            o.w = __builtin_bit_cast(ushort_t, (__bf16)tile[(rq * 4 + 3) * 68 + cl]);
            *(ushort4*)(op + (size_t)(bx * 64 + cl) * R + by * 64 + rq * 4) = o;
        }
    }
}

// ---------------- router: LDS-transposed Wr, 8 tokens/wave, block-aggregated atomics ----------------
__launch_bounds__(256)
__global__ void k_router(const float* __restrict__ x, const float* __restrict__ Wr,
                         const float* __restrict__ br, int* __restrict__ cnt,
                         int* __restrict__ tok, int* __restrict__ slot,
                         float* __restrict__ wslot, ushort_t* __restrict__ xb) {
    __shared__ float WrT[NEXP * DMODEL];
    __shared__ int   te0[32], te1[32];
    __shared__ int   lcnt[NEXP], gbase[NEXP];

    const int tid = threadIdx.x;
    const int wv = tid >> 6, lane = tid & 63;

#pragma unroll
    for (int i = 0; i < 6; ++i) {
        int idx4 = i * 256 + tid;
        float4 v = ((const float4*)Wr)[idx4];
        int flat = idx4 * 4;
        int d = flat >> 3, e0 = flat & 7;
        WrT[(e0 + 0) * DMODEL + d] = v.x;
        WrT[(e0 + 1) * DMODEL + d] = v.y;
        WrT[(e0 + 2) * DMODEL + d] = v.z;
        WrT[(e0 + 3) * DMODEL + d] = v.w;
    }
    if (tid < NEXP) lcnt[tid] = 0;
    float brv[8];
#pragma unroll
    for (int e = 0; e < 8; ++e) brv[e] = br[e];
    __syncthreads();

#pragma unroll 1
    for (int it = 0; it < 8; ++it) {
        int t = blockIdx.x * 32 + wv * 8 + it;
        const float* xr = x + (size_t)t * DMODEL;
        float4 xv[3];
#pragma unroll
        for (int j = 0; j < 3; ++j) xv[j] = *(const float4*)(xr + (j * 64 + lane) * 4);
#pragma unroll
        for (int j = 0; j < 3; ++j) {
            int base = (j * 64 + lane) * 4;
            ushort4 o;
            o.x = __builtin_bit_cast(ushort_t, (__bf16)xv[j].x);
            o.y = __builtin_bit_cast(ushort_t, (__bf16)xv[j].y);
            o.z = __builtin_bit_cast(ushort_t, (__bf16)xv[j].z);
            o.w = __builtin_bit_cast(ushort_t, (__bf16)xv[j].w);
            *(ushort4*)(xb + (size_t)t * DMODEL + base) = o;
        }
        float lg[8];
#pragma unroll
        for (int e = 0; e < 8; ++e) {
            float s = 0.f;
#pragma unroll
            for (int j = 0; j < 3; ++j) {
                const float4 wv4 = *(const float4*)(&WrT[e * DMODEL + (j * 64 + lane) * 4]);
                s += xv[j].x * wv4.x;
                s += xv[j].y * wv4.y;
                s += xv[j].z * wv4.z;
                s += xv[j].w * wv4.w;
            }
#pragma unroll
            for (int o = 32; o > 0; o >>= 1) s += __shfl_xor(s, o);
            lg[e] = s + brv[e];
        }
        if (lane == 0) {
            int e0 = 0; float b0 = lg[0];
#pragma unroll
            for (int e = 1; e < 8; ++e) if (lg[e] > b0) { b0 = lg[e]; e0 = e; }
            int e1 = -1; float b1v = -1e30f;
#pragma unroll
            for (int e = 0; e < 8; ++e) if (e != e0 && lg[e] > b1v) { b1v = lg[e]; e1 = e; }
            float w0 = 1.f / (1.f + __expf(b1v - b0));
            float w1 = 1.f - w0;
            int lt = wv * 8 + it;
            te0[lt] = e0; te1[lt] = e1;
            wslot[2 * t] = w0; wslot[2 * t + 1] = w1;
        }
    }
    __syncthreads();

    int myE = 0, myPos = 0, myTok = 0, myK = 0;
    if (tid < 64) {
        int lt = tid >> 1; myK = tid & 1;
        myE = myK ? te1[lt] : te0[lt];
        myTok = blockIdx.x * 32 + lt;
        myPos = atomicAdd(&lcnt[myE], 1);
    }
    __syncthreads();
    if (tid < NEXP) gbase[tid] = atomicAdd(&cnt[tid], lcnt[tid]);
    __syncthreads();
    if (tid < 64) {
        int g = gbase[myE] + myPos;
        tok[myE * TOKENS + g] = myTok;
        slot[myE * TOKENS + g] = 2 * myTok + myK;
    }
}

// ---------------- tile scheduler: single BM=256 table ----------------
// sch[0]=nT, sch[2..9]=baseH prefix, sch[16..]= tiles (e<<20|m0)
__global__ void k_sched(const int* __restrict__ cnt, int* __restrict__ sch) {
    if (threadIdx.x == 0) {
        int base = 0, n = 0;
        for (int e = 0; e < NEXP; ++e) {
            sch[2 + e] = base;
            int ce = cnt[e];
            for (int m = 0; m < ce; m += 256) sch[16 + n++] = (e << 20) | m;
            base += ce;
        }
        sch[0] = n;
    }
}

// ---------------- 4-phase/K-tile counted-vmcnt GEMM ----------------
// BM=BN=256, BK=64, 8 waves (2x4), wave-tile 128x64, 2x64KB LDS dbuf.
// LDS buffer layout: [A-ks0 16K][A-ks1 16K][B-ks0 16K][B-ks1 16K]
//   region addr = row*64 + ((blk ^ ((row>>1)&3))<<4), 64B rows (2-way conflict = free)

#define ISSUE(c, kt1, BOFF)                                                            \
    {                                                                                  \
        _Pragma("unroll")                                                              \
        for (int i_ = 0; i_ < 2; ++i_) {                                               \
            const ushort_t* s_ = (((c) & 1) ? bPtr[i_] : aPtr[i_]) + (kt1) * 64 + (((c) >> 1) * 32); \
            gload16(s_, ldsB + (BOFF) + (((c) & 1) ? 32768 : 0) + (((c) >> 1) * 16384) \
                            + w * 2048 + i_ * 1024);                                   \
        }                                                                              \
    }

#define MFMA16(NH)                                                                     \
    __builtin_amdgcn_s_setprio(1);                                                     \
    _Pragma("unroll")                                                                  \
    for (int mi = 0; mi < 8; ++mi) {                                                   \
        acc[mi][(NH)*2 + 0] = __builtin_amdgcn_mfma_f32_16x16x32_bf16(af[mi], bf[0], acc[mi][(NH)*2 + 0], 0, 0, 0); \
        acc[mi][(NH)*2 + 1] = __builtin_amdgcn_mfma_f32_16x16x32_bf16(af[mi], bf[1], acc[mi][(NH)*2 + 1], 0, 0, 0); \
    }                                                                                  \
    __builtin_amdgcn_s_setprio(0);

#define TILE(kt, BUFOFF, PF, LAST)                                                     \
    {                                                                                  \
        const char* bufL = ldsB + (BUFOFF);                                            \
        bf16x8 af[8], bf[2];                                                           \
        /* phase 0: ks0 nh0 */                                                         \
        _Pragma("unroll")                                                              \
        for (int mi = 0; mi < 8; ++mi) af[mi] = *(const bf16x8*)(bufL + abase + mi * 1024); \
        bf[0] = *(const bf16x8*)(bufL + bbase + 0 * 1024);                             \
        bf[1] = *(const bf16x8*)(bufL + bbase + 1 * 1024);                             \
        if (PF) ISSUE(0, (kt) + 1, (BUFOFF) ^ 65536);                                  \
        wg_barrier();                                                                  \
        MFMA16(0)                                                                      \
        wg_barrier();                                                                  \
        /* phase 1: ks0 nh1 */                                                         \
        bf[0] = *(const bf16x8*)(bufL + bbase + 2 * 1024);                             \
        bf[1] = *(const bf16x8*)(bufL + bbase + 3 * 1024);                             \
        if (PF) ISSUE(1, (kt) + 1, (BUFOFF) ^ 65536);                                  \
        wg_barrier();                                                                  \
        MFMA16(1)                                                                      \
        if (LAST) { VMCNT(0); } else { VMCNT(4); }                                     \
        wg_barrier();                                                                  \
        /* phase 2: ks1 nh0 */                                                         \
        _Pragma("unroll")                                                              \
        for (int mi = 0; mi < 8; ++mi) af[mi] = *(const bf16x8*)(bufL + abase + 16384 + mi * 1024); \
        bf[0] = *(const bf16x8*)(bufL + bbase + 16384 + 0 * 1024);                     \
        bf[1] = *(const bf16x8*)(bufL + bbase + 16384 + 1 * 1024);                     \
        if (PF) ISSUE(2, (kt) + 1, (BUFOFF) ^ 65536);                                  \
        wg_barrier();                                                                  \
        MFMA16(0)                                                                      \
        wg_barrier();                                                                  \
        /* phase 3: ks1 nh1 */                                                         \
        bf[0] = *(const bf16x8*)(bufL + bbase + 16384 + 2 * 1024);                     \
        bf[1] = *(const bf16x8*)(bufL + bbase + 16384 + 3 * 1024);                     \
        if (PF) ISSUE(3, (kt) + 1, (BUFOFF) ^ 65536);                                  \
        wg_barrier();                                                                  \
        MFMA16(1)                                                                      \
        VMCNT(4);                                                                      \
        wg_barrier();                                                                  \
    }

template<bool STAGE1>
__launch_bounds__(512, 1)
__global__ void k_gemm8(const ushort_t* __restrict__ Abase, const int* __restrict__ tok,
                        const int* __restrict__ slot, const ushort_t* __restrict__ Wb,
                        const float* __restrict__ bias, void* __restrict__ outp,
                        const int* __restrict__ cnt, const int* __restrict__ sch) {
    constexpr int KR  = STAGE1 ? DMODEL : DHID;
    constexpr int NCn = STAGE1 ? DHID : DMODEL;
    constexpr int NT  = STAGE1 ? (DMODEL / 64) : (DHID / 2 / 64);   // 12 or 24

    // bijective XCD swizzle (gridDim.x == 40, 40 % 8 == 0 -> xcd*5 + bx/8)
    const int bx = blockIdx.x;
    const int tile = (bx & 7) * 5 + (bx >> 3);
    const int nT = sch[0];
    if (tile >= nT) return;
    const int ent = sch[16 + tile];
    const int e = ent >> 20, m0 = ent & 0xFFFFF;
    const int ce = cnt[e];
    const int bH = sch[2 + e];
    const int n0 = blockIdx.y * 256;
    const int kbase = STAGE1 ? 0 : (int)blockIdx.z * (DHID / 2);

    __shared__ ushort_t lds[65536];     // 128 KB: 2 x 64KB buffers
    char* ldsB = (char*)lds;

    const int tid = threadIdx.x, lane = tid & 63, w = tid >> 6;
    const int wm = w >> 2, wn = w & 3;          // 2 x 4 waves
    const int wmBase = wm * 128, wnBase = wn * 64;
    const int fr = lane & 15, fg = lane >> 4;

    // staging source pointers (inverse-swizzled global columns)
    const ushort_t* aPtr[2];
    const ushort_t* bPtr[2];
#pragma unroll
    for (int i = 0; i < 2; ++i) {
        int j = w * 2 + i;
        int row = j * 16 + (lane >> 2);
        int gblk = (lane & 3) ^ ((row >> 1) & 3);
        int gi = min(m0 + row, ce - 1);
        size_t ar = STAGE1 ? (size_t)tok[e * TOKENS + gi] : (size_t)(bH + gi);
        aPtr[i] = Abase + ar * KR + kbase + gblk * 8;
        bPtr[i] = Wb + ((size_t)e * NCn + n0 + row) * KR + kbase + gblk * 8;
    }

    // ds_read base addrs (swizzle term invariant under mi*16 / +32-row / ks steps)
    const int arow0 = wmBase + fr;
    const int abase = arow0 * 64 + ((fg ^ ((arow0 >> 1) & 3)) << 4);
    const int brow0 = wnBase + fr;
    const int bbase = 32768 + brow0 * 64 + ((fg ^ ((brow0 >> 1) & 3)) << 4);

    f32x4 acc[8][4] = {};

    // prologue: all 4 chunks of tile 0 into buf0
    ISSUE(0, 0, 0); ISSUE(1, 0, 0); ISSUE(2, 0, 0); ISSUE(3, 0, 0);
    VMCNT(4);           // ks0 chunks of tile 0 landed; ks1 still in flight
    wg_barrier();

#pragma unroll 1
    for (int kt = 0; kt < NT - 2; kt += 2) {
        TILE(kt, 0, 1, 0)
        TILE(kt + 1, 65536, 1, 0)
    }
    TILE(NT - 2, 0, 1, 0)
    TILE(NT - 1, 65536, 0, 1)

    // ---- epilogue ----
    float bv[4];
#pragma unroll
    for (int ni = 0; ni < 4; ++ni)
        bv[ni] = bias[e * NCn + n0 + wnBase + ni * 16 + fr];
#pragma unroll
    for (int mi = 0; mi < 8; ++mi) {
#pragma unroll
        for (int r4 = 0; r4 < 4; ++r4) {
            int gi = m0 + wmBase + mi * 16 + fg * 4 + r4;
            if (gi < ce) {
                if constexpr (STAGE1) {
                    size_t orow = (size_t)(bH + gi);
#pragma unroll
                    for (int ni = 0; ni < 4; ++ni) {
                        int col = n0 + wnBase + ni * 16 + fr;
                        float v = gelu_tanh(acc[mi][ni][r4] + bv[ni]);
                        ((ushort_t*)outp)[orow * DHID + col] =
                            __builtin_bit_cast(ushort_t, (__bf16)v);
                    }
                } else {
                    size_t orow = (size_t)blockIdx.z * 8192 + (size_t)slot[e * TOKENS + gi];
                    float badd = (blockIdx.z == 0) ? 1.f : 0.f;
#pragma unroll
                    for (int ni = 0; ni < 4; ++ni) {
                        int col = n0 + wnBase + ni * 16 + fr;
                        float v = acc[mi][ni][r4] + badd * bv[ni];
                        ((ushort_t*)outp)[orow * DMODEL + col] =
                            __builtin_bit_cast(ushort_t, (__bf16)v);
                    }
                }
            }
        }
    }
}

// ---------------- combine 2 slots x 2 split-K halves (bf16) + LayerNorm ----------------
__global__ void k_ln(const ushort_t* __restrict__ Y2, const float* __restrict__ wslot,
                     const float* __restrict__ g, const float* __restrict__ b,
                     float* __restrict__ out) {
    int wv = threadIdx.x >> 6, lane = threadIdx.x & 63;
    int t = blockIdx.x * 4 + wv;
    const ushort_t* r00 = Y2 + (size_t)(2 * t) * DMODEL;
    const ushort_t* r01 = Y2 + (size_t)(8192 + 2 * t) * DMODEL;
    const ushort_t* r10 = r00 + DMODEL;
    const ushort_t* r11 = r01 + DMODEL;
    float w0 = wslot[2 * t], w1 = wslot[2 * t + 1];
    float4 v[3];
    float s = 0.f, ss = 0.f;
#pragma unroll
    for (int j = 0; j < 3; ++j) {
        int base = (j * 64 + lane) * 4;
        ushort4 a0 = *(const ushort4*)(r00 + base);
        ushort4 a1 = *(const ushort4*)(r01 + base);
        ushort4 c0 = *(const ushort4*)(r10 + base);
        ushort4 c1 = *(const ushort4*)(r11 + base);
        float4 c;
        c.x = w0 * (bf2f(a0.x) + bf2f(a1.x)) + w1 * (bf2f(c0.x) + bf2f(c1.x));
        c.y = w0 * (bf2f(a0.y) + bf2f(a1.y)) + w1 * (bf2f(c0.y) + bf2f(c1.y));
        c.z = w0 * (bf2f(a0.z) + bf2f(a1.z)) + w1 * (bf2f(c0.z) + bf2f(c1.z));
        c.w = w0 * (bf2f(a0.w) + bf2f(a1.w)) + w1 * (bf2f(c0.w) + bf2f(c1.w));
        v[j] = c;
        s  += c.x + c.y + c.z + c.w;
        ss += c.x * c.x + c.y * c.y + c.z * c.z + c.w * c.w;
    }
#pragma unroll
    for (int o = 32; o > 0; o >>= 1) { s += __shfl_xor(s, o); ss += __shfl_xor(ss, o); }
    float mu = s * (1.f / 768.f);
    float var = ss * (1.f / 768.f) - mu * mu;
    float inv = rsqrtf(var + 1e-5f);
    float* row = out + (size_t)t * DMODEL;
#pragma unroll
    for (int j = 0; j < 3; ++j) {
        int base = (j * 64 + lane) * 4;
        float4 gv = *(const float4*)(g + base);
        float4 bv = *(const float4*)(b + base);
        float4 o4;
        o4.x = (v[j].x - mu) * inv * gv.x + bv.x;
        o4.y = (v[j].y - mu) * inv * gv.y + bv.y;
        o4.z = (v[j].z - mu) * inv * gv.z + bv.z;
        o4.w = (v[j].w - mu) * inv * gv.w + bv.w;
        *(float4*)(row + base) = o4;
    }
}

extern "C" void kernel_launch(void* const* d_in, const int* in_sizes, int n_in,
                              void* d_out, int out_size, void* d_ws, size_t ws_size,
                              hipStream_t stream) {
    const float* x    = (const float*)d_in[0];
    const float* Wr   = (const float*)d_in[1];
    const float* br   = (const float*)d_in[2];
    const float* W1   = (const float*)d_in[3];
    const float* b1   = (const float*)d_in[4];
    const float* W2   = (const float*)d_in[5];
    const float* b2   = (const float*)d_in[6];
    const float* ln_g = (const float*)d_in[7];
    const float* ln_b = (const float*)d_in[8];
    float* out = (float*)d_out;

    char* ws = (char*)d_ws;
    int*      cnt   = (int*)(ws + 0);                    //    32 B
    int*      sch   = (int*)(ws + 64);                   //   ~1 KB
    int*      tok   = (int*)(ws + 4096);                 //   128 KB
    int*      slot  = (int*)(ws + 135168);               //   128 KB
    float*    wslot = (float*)(ws + 266240);             //    32 KB
    ushort_t* xb    = (ushort_t*)(ws + 327680);          //  6.29 MB
    ushort_t* W1t   = (ushort_t*)(ws + 6619136);         // 37.75 MB  [e][h][d]
    ushort_t* W2t   = (ushort_t*)(ws + 44367872);        // 37.75 MB  [e][o][h]
    ushort_t* H     = (ushort_t*)(ws + 82116608);        // 50.33 MB  [8192][3072] bf16, packed
    ushort_t* Y2    = (ushort_t*)(ws + 132448256);       // 25.17 MB  [2][8192][768] bf16

    hipMemsetAsync(cnt, 0, 32, stream);

    k_transpose_cvt<<<dim3(DHID / 64, DMODEL / 64, NEXP), dim3(256), 0, stream>>>(W1, W1t, DMODEL, DHID);
    k_transpose_cvt<<<dim3(DMODEL / 64, DHID / 64, NEXP), dim3(256), 0, stream>>>(W2, W2t, DHID, DMODEL);
    k_router<<<dim3(TOKENS / 32), dim3(256), 0, stream>>>(x, Wr, br, cnt, tok, slot, wslot, xb);
    k_sched<<<dim3(1), dim3(64), 0, stream>>>(cnt, sch);

    // stage A: H[bH+gi] = gelu(X[tok] @ W1t^T + b1)    BM=256 BN=256, K=768
    k_gemm8<true><<<dim3(MAXT, DHID / 256, 1), dim3(512), 0, stream>>>(
        xb, tok, slot, W1t, b1, H, cnt, sch);
    // stage B: Y2[z][slot] = H @ W2t^T (+b2 if z==0)   BM=256 BN=256, split-K 2x1536
    k_gemm8<false><<<dim3(MAXT, DMODEL / 256, 2), dim3(512), 0, stream>>>(
        H, tok, slot, W2t, b2, Y2, cnt, sch);

    k_ln<<<dim3(TOKENS / 4), dim3(256), 0, stream>>>(Y2, wslot, ln_g, ln_b, out);
}